// Round 9
// baseline (681.526 us; speedup 1.0000x reference)
//
#include <hip/hip_runtime.h>

// LocalAttention: windowed MHA. B=8, C=512, H=W=128, WS=8
// -> N=2048 windows x L=64 tokens, NH=4, hd=128.
//
// Main path:
//   conv_wt:  w_in/w_out f32 -> bf16 FRAGMENT-TILED
//   pack_x:   x f32 -> bf16 fragment-tiled xw[n][c8][tok][8], coalesced
//   qkv_attn: one block per (window, head), XCD-swizzled; QKV GEMM
//             (xw DMA-staged, tiled weights, BALANCED wave->tile map),
//             softmax, PV -> ctx chunk in ws (L2-resident via nc>=4).
//   outproj:  GEMM out = w_out * ctx^T + b_out -> NCHW f32.
// Fallback: R3 fused kernel (plain weights).

typedef __attribute__((ext_vector_type(8))) short s16x8;   // 8 bf16
typedef __attribute__((ext_vector_type(4))) float f32x4;   // MFMA C/D

#define C_TOT 512
#define HWIMG 128
#define CH_STRIDE (HWIMG * HWIMG) /* 16384 */
#define NWIN 2048
#define XW_ELEMS ((size_t)NWIN * 64 * 512)     /* 67,108,864 bf16 */
#define XW_BYTES (XW_ELEMS * 2ull)             /* 134,217,728 B  */
#define WIT_ELEMS 786432ull                    /* tiled w_in  */
#define WOT_ELEMS 262144ull                    /* tiled w_out */
#define WBF_ELEMS 1048576ull
#define CTX_BYTES_FULL (XW_ELEMS * 2ull)       /* 134MB */

__device__ __forceinline__ unsigned short f2bf(float f) {
  unsigned u = __float_as_uint(f);
  u += 0x7FFFu + ((u >> 16) & 1u);       // RNE
  return (unsigned short)(u >> 16);
}

__device__ __forceinline__ unsigned cvt_pk_bf16(float a, float b) {
  unsigned r;
  asm("v_cvt_pk_bf16_f32 %0, %1, %2" : "=v"(r) : "v"(a), "v"(b));
  return r;   // lo = bf16(a), hi = bf16(b)
}

// async global->LDS DMA, 16B per lane; LDS dest = wave-uniform base + lane*16
__device__ __forceinline__ void gload_lds16(const void* g, void* l) {
  __builtin_amdgcn_global_load_lds(
      (const __attribute__((address_space(1))) unsigned int*)g,
      (__attribute__((address_space(3))) unsigned int*)l, 16, 0, 0);
}

// plain bf16 conversion (fallback path only)
__global__ void conv_w_kernel(const float* __restrict__ w_in,
                              const float* __restrict__ w_out,
                              unsigned short* __restrict__ wbf) {
  int i = blockIdx.x * blockDim.x + threadIdx.x;   // grid covers 1048576
  const int NIN = 3 * C_TOT * C_TOT;               // 786432
  float v = (i < NIN) ? w_in[i] : w_out[i - NIN];
  wbf[i] = f2bf(v);
}

// fragment-tiled weights:
//  wit[h4][m24][c8 64][l15 16][e8]: row = t*512 + h*128 + 16*(m%8) + l15
//  wot[m32][c8 64][l15 16][e8]:     row od = 16m + l15, chan = 8*c8+e
__global__ void conv_wt_kernel(const float* __restrict__ w_in,
                               const float* __restrict__ w_out,
                               unsigned short* __restrict__ wit,
                               unsigned short* __restrict__ wot) {
  int i = blockIdx.x * blockDim.x + threadIdx.x;   // 0..1048575
  const int NIN = 3 * C_TOT * C_TOT;               // 786432
  if (i < NIN) {
    const int e = i >> 9, c = i & 511;
    const int t = e >> 9, rem = e & 511;
    const int h = rem >> 7, d = rem & 127;
    const int m = t * 8 + (d >> 4), l = d & 15;
    const int c8 = c >> 3, ec = c & 7;
    wit[(((size_t)(h * 24 + m) * 64 + c8) << 7) + l * 8 + ec] = f2bf(w_in[i]);
  } else {
    const int j = i - NIN;                         // 0..262143
    const int od = j >> 9, c = j & 511;
    const int m = od >> 4, l = od & 15;
    const int c8 = c >> 3, ec = c & 7;
    wot[(((size_t)m * 64 + c8) << 7) + l * 8 + ec] = f2bf(w_out[j]);
  }
}

// pack_x: fully-coalesced float4 reads + in-register transpose.
__global__ void __launch_bounds__(256)
pack_x_kernel(const float* __restrict__ x, unsigned short* __restrict__ xw) {
  const int blk = blockIdx.x;
  const int bb  = blk >> 8;
  const int hw  = (blk >> 4) & 15;
  const int og4 = blk & 15;
  const int t   = threadIdx.x;
  const int p0  = 4 * t;                 // pixel in strip [0,1024)
  const int r   = p0 >> 7;               // row in window  [0,8)
  const int col0 = p0 & 127;             // col in strip   [0,128)
  const int n   = bb * 256 + hw * 16 + (col0 >> 3);
  const int tok0 = r * 8 + (col0 & 7);
  const float* xs = x + (size_t)bb * C_TOT * CH_STRIDE
                  + (size_t)hw * 1024 + p0;
  unsigned short* pw = xw + (size_t)n * 32768;
#pragma unroll
  for (int jo = 0; jo < 4; ++jo) {
    const int o = og4 * 4 + jo;          // channel octet 0..63
    float4 f[8];
#pragma unroll
    for (int k = 0; k < 8; ++k)
      f[k] = *(const float4*)(xs + (size_t)(8 * o + k) * CH_STRIDE);
#pragma unroll
    for (int i = 0; i < 4; ++i) {
      s16x8 pk;
      if (i == 0) {
        pk[0]=(short)f2bf(f[0].x); pk[1]=(short)f2bf(f[1].x); pk[2]=(short)f2bf(f[2].x); pk[3]=(short)f2bf(f[3].x);
        pk[4]=(short)f2bf(f[4].x); pk[5]=(short)f2bf(f[5].x); pk[6]=(short)f2bf(f[6].x); pk[7]=(short)f2bf(f[7].x);
      } else if (i == 1) {
        pk[0]=(short)f2bf(f[0].y); pk[1]=(short)f2bf(f[1].y); pk[2]=(short)f2bf(f[2].y); pk[3]=(short)f2bf(f[3].y);
        pk[4]=(short)f2bf(f[4].y); pk[5]=(short)f2bf(f[5].y); pk[6]=(short)f2bf(f[6].y); pk[7]=(short)f2bf(f[7].y);
      } else if (i == 2) {
        pk[0]=(short)f2bf(f[0].z); pk[1]=(short)f2bf(f[1].z); pk[2]=(short)f2bf(f[2].z); pk[3]=(short)f2bf(f[3].z);
        pk[4]=(short)f2bf(f[4].z); pk[5]=(short)f2bf(f[5].z); pk[6]=(short)f2bf(f[6].z); pk[7]=(short)f2bf(f[7].z);
      } else {
        pk[0]=(short)f2bf(f[0].w); pk[1]=(short)f2bf(f[1].w); pk[2]=(short)f2bf(f[2].w); pk[3]=(short)f2bf(f[3].w);
        pk[4]=(short)f2bf(f[4].w); pk[5]=(short)f2bf(f[5].w); pk[6]=(short)f2bf(f[6].w); pk[7]=(short)f2bf(f[7].w);
      }
      *(s16x8*)(pw + ((size_t)o * 64 + tok0 + i) * 8) = pk;
    }
  }
}

// ---- kernel B LDS layout (80KB) ----
#define BQO 0        // Q [tok 64][d 128] bf16, row 256B, swz ((tok&7)<<4)
#define BKO 16384
#define BVO 32768    // V^T [d 128][tok 64] bf16, row 128B, swz ((d&7)<<4)
#define BXS 49152    // xw slice dbuf: 2 x 16KB (K=128 slices, tiled linear)
#define BPO 49152    // P [tq 64][tk 64] bf16 normalized - OVERLAYS stage buf0
#define BLDS 81920

__global__ void __launch_bounds__(512, 4)
qkv_attn_kernel(const unsigned short* __restrict__ xw,   // tiled bf16 x
                const float* __restrict__ bin,
                const unsigned short* __restrict__ wit,  // tiled w_in bf16
                unsigned short* __restrict__ ctx,        // chunk base, tiled
                int n0) {
  __shared__ __align__(16) unsigned char sm[BLDS];

  const int tid  = threadIdx.x;
  const int wv   = tid >> 6;      // wave 0..7
  const int lane = tid & 63;
  const int l15  = lane & 15;
  const int qd   = lane >> 4;
  const int swA  = (l15 & 7) << 4;

  // XCD swizzle: blk = 32k + 8h + g -> window wrel = 8k + g, head h.
  const int blk = blockIdx.x;
  const int g   = blk & 7;
  const int q   = blk >> 3;
  const int h   = q & 3;
  const int nrel = (q >> 2) * 8 + g;
  const unsigned short* xww = xw + (size_t)(n0 + nrel) * 32768;

  const float SCALE = 0.08838834764831845f;  // 1/sqrt(128)
  const float L2E   = 1.4426950408889634f;

  // ====== QKV: balanced map — wave wv owns tiles {wv, wv+8, wv+16} ======
  // mi = type (0=Q,1=K,2=V); dim-slice within head = [16*wv, 16*wv+16).
  f32x4 acc[3][4];
#pragma unroll
  for (int a = 0; a < 3; ++a)
#pragma unroll
    for (int b2 = 0; b2 < 4; ++b2) acc[a][b2] = (f32x4){0.f, 0.f, 0.f, 0.f};

  const int d128 = 16 * wv;
  const unsigned short* arow[3];
#pragma unroll
  for (int mi = 0; mi < 3; ++mi)
    arow[mi] = wit + ((size_t)(h * 24 + wv + 8 * mi) << 13) + l15 * 8;

  // prologue: DMA slice 0 (2 passes x 8KB)
#pragma unroll
  for (int p = 0; p < 2; ++p)
    gload_lds16(xww + p * 4096 + tid * 8, &sm[BXS + p * 8192 + (wv << 10)]);
  __syncthreads();

  for (int s = 0; s < 4; ++s) {
    if (s < 3) {
#pragma unroll
      for (int p = 0; p < 2; ++p)
        gload_lds16(xww + (size_t)(s + 1) * 8192 + p * 4096 + tid * 8,
                    &sm[BXS + ((s + 1) & 1) * 16384 + p * 8192 + (wv << 10)]);
    }
    const int cur = BXS + (s & 1) * 16384;
#pragma unroll
    for (int j = 0; j < 4; ++j) {
      const int c8g = 16 * s + 4 * j + qd;         // global channel octet
      const int lb = cur + ((4 * j + qd) << 10);   // local c8 block
      s16x8 bx[4];
#pragma unroll
      for (int ni = 0; ni < 4; ++ni)
        bx[ni] = *(const s16x8*)(&sm[lb + (16 * ni + l15) * 16]);
#pragma unroll
      for (int mi = 0; mi < 3; ++mi) {
        const s16x8 af = *(const s16x8*)(arow[mi] + ((size_t)c8g << 7));
#pragma unroll
        for (int ni = 0; ni < 4; ++ni)
          acc[mi][ni] = __builtin_amdgcn_mfma_f32_16x16x32_bf16(af, bx[ni], acc[mi][ni], 0, 0, 0);
      }
    }
    __syncthreads();   // drains vmcnt (DMA done) + all reads of cur complete
  }

  // epilogue: Q/K -> [tok][d] packed b64 (cvt_pk); V -> [d][tok] b16 scatter
#pragma unroll
  for (int mi = 0; mi < 3; ++mi) {
    const int e0 = mi * 512 + h * 128 + d128 + 4 * qd;
    const float bi0 = bin[e0], bi1 = bin[e0 + 1], bi2 = bin[e0 + 2], bi3 = bin[e0 + 3];
#pragma unroll
    for (int ni = 0; ni < 4; ++ni) {
      const int tok = 16 * ni + l15;
      if (mi < 2) {
        const unsigned lo = cvt_pk_bf16(acc[mi][ni][0] + bi0, acc[mi][ni][1] + bi1);
        const unsigned hi = cvt_pk_bf16(acc[mi][ni][2] + bi2, acc[mi][ni][3] + bi3);
        const unsigned long long pk = (unsigned long long)lo | ((unsigned long long)hi << 32);
        const int base = (mi == 0) ? BQO : BKO;
        *(unsigned long long*)(&sm[base + tok * 256 + ((2 * (d128 + 4 * qd)) ^ swA)]) = pk;
      } else {
        const unsigned short h0 = f2bf(acc[mi][ni][0] + bi0);
        const unsigned short h1 = f2bf(acc[mi][ni][1] + bi1);
        const unsigned short h2 = f2bf(acc[mi][ni][2] + bi2);
        const unsigned short h3 = f2bf(acc[mi][ni][3] + bi3);
        const int vd = d128 + 4 * qd;
        *(unsigned short*)(&sm[BVO + (vd    ) * 128 + ((2 * tok) ^ (((vd    ) & 7) << 4))]) = h0;
        *(unsigned short*)(&sm[BVO + (vd + 1) * 128 + ((2 * tok) ^ (((vd + 1) & 7) << 4))]) = h1;
        *(unsigned short*)(&sm[BVO + (vd + 2) * 128 + ((2 * tok) ^ (((vd + 2) & 7) << 4))]) = h2;
        *(unsigned short*)(&sm[BVO + (vd + 3) * 128 + ((2 * tok) ^ (((vd + 3) & 7) << 4))]) = h3;
      }
    }
  }
  __syncthreads();

  // ====== S = Q K^T, softmax (waves 0..3 own full rows), normalized P ======
  if (wv < 4) {
    f32x4 s[4];
#pragma unroll
    for (int a = 0; a < 4; ++a) s[a] = (f32x4){0.f, 0.f, 0.f, 0.f};
    const int tqa = 16 * wv + l15;
#pragma unroll
    for (int ks = 0; ks < 4; ++ks) {
      const int c0 = 32 * ks + 8 * qd;
      const s16x8 aq = *(const s16x8*)(&sm[BQO + tqa * 256 + ((2 * c0) ^ swA)]);
#pragma unroll
      for (int ni = 0; ni < 4; ++ni) {
        const int tk = 16 * ni + l15;
        const s16x8 bk = *(const s16x8*)(&sm[BKO + tk * 256 + ((2 * c0) ^ swA)]);
        s[ni] = __builtin_amdgcn_mfma_f32_16x16x32_bf16(aq, bk, s[ni], 0, 0, 0);
      }
    }
    float sv[4][4];
#pragma unroll
    for (int ni = 0; ni < 4; ++ni)
#pragma unroll
      for (int i = 0; i < 4; ++i) sv[ni][i] = s[ni][i] * SCALE;
    float m[4];
#pragma unroll
    for (int i = 0; i < 4; ++i)
      m[i] = fmaxf(fmaxf(sv[0][i], sv[1][i]), fmaxf(sv[2][i], sv[3][i]));
#pragma unroll
    for (int d = 1; d < 16; d <<= 1)
#pragma unroll
      for (int i = 0; i < 4; ++i) m[i] = fmaxf(m[i], __shfl_xor(m[i], d));
    float p[4][4], sum[4] = {0.f, 0.f, 0.f, 0.f};
#pragma unroll
    for (int ni = 0; ni < 4; ++ni)
#pragma unroll
      for (int i = 0; i < 4; ++i) {
        p[ni][i] = exp2f((sv[ni][i] - m[i]) * L2E);
        sum[i] += p[ni][i];
      }
#pragma unroll
    for (int d = 1; d < 16; d <<= 1)
#pragma unroll
      for (int i = 0; i < 4; ++i) sum[i] += __shfl_xor(sum[i], d);
    float rinv[4];
#pragma unroll
    for (int i = 0; i < 4; ++i) rinv[i] = 1.0f / sum[i];
#pragma unroll
    for (int ni = 0; ni < 4; ++ni)
#pragma unroll
      for (int i = 0; i < 4; ++i) {
        const int tqr = 16 * wv + 4 * qd + i;
        const int tk = 16 * ni + l15;
        *(unsigned short*)(&sm[BPO + tqr * 128 + ((2 * tk) ^ ((tqr & 7) << 4))]) =
            f2bf(p[ni][i] * rinv[i]);
      }
  }
  __syncthreads();

  // ====== PV: ctx[tq][vd] = sum_tk P[tq][tk] V^T[vd][tk]; write global ======
  {
    const int mq = wv >> 1;              // tq tile
    const int nb = (wv & 1) * 4;         // vd tile base
    f32x4 cacc[4];
#pragma unroll
    for (int a = 0; a < 4; ++a) cacc[a] = (f32x4){0.f, 0.f, 0.f, 0.f};
    const int tqa = 16 * mq + l15;
#pragma unroll
    for (int ks = 0; ks < 2; ++ks) {
      const int c0 = 32 * ks + 8 * qd;
      const s16x8 ap = *(const s16x8*)(&sm[BPO + tqa * 128 + ((2 * c0) ^ swA)]);
#pragma unroll
      for (int j = 0; j < 4; ++j) {
        const int vda = 16 * (nb + j) + l15;
        const s16x8 bv = *(const s16x8*)(&sm[BVO + vda * 128 + ((2 * c0) ^ swA)]);
        cacc[j] = __builtin_amdgcn_mfma_f32_16x16x32_bf16(ap, bv, cacc[j], 0, 0, 0);
      }
    }
    unsigned short* ctxn = ctx + (size_t)nrel * 32768;
#pragma unroll
    for (int j = 0; j < 4; ++j) {
      const int vd = 16 * (nb + j) + l15;
      const int c  = h * 128 + vd;
      const int c8 = c >> 3, e = c & 7;
#pragma unroll
      for (int i = 0; i < 4; ++i) {
        const int tq = 16 * mq + 4 * qd + i;
        ctxn[((size_t)c8 * 64 + tq) * 8 + e] = f2bf(cacc[j][i]);
      }
    }
  }
}

// ====== out-proj: out[od][tok] = sum_c wo[od][c]*ctx[tok][c] + b, NCHW ======
#define OXS 0        // ctx slice dbuf: 2 x 16KB
#define OLDS 32768

__global__ void __launch_bounds__(512, 4)
outproj_kernel(const unsigned short* __restrict__ ctx,   // chunk base, tiled
               const unsigned short* __restrict__ wot,   // tiled w_out bf16
               const float* __restrict__ bout,
               float* __restrict__ out, int n0) {
  __shared__ __align__(16) unsigned char sm[OLDS];

  const int tid  = threadIdx.x;
  const int wv   = tid >> 6;
  const int lane = tid & 63;
  const int l15  = lane & 15;
  const int qd   = lane >> 4;

  const int nrel = blockIdx.x;
  const int n  = n0 + nrel;
  const int bb = n >> 8, hw = (n >> 4) & 15, ww = n & 15;
  const size_t wbase = (size_t)bb * C_TOT * CH_STRIDE
                     + (size_t)(hw * 8) * HWIMG + (size_t)(ww * 8);
  const unsigned short* ctxn = ctx + (size_t)nrel * 32768;

  f32x4 oacc[4][4];
#pragma unroll
  for (int a = 0; a < 4; ++a)
#pragma unroll
    for (int b2 = 0; b2 < 4; ++b2) oacc[a][b2] = (f32x4){0.f, 0.f, 0.f, 0.f};

  const unsigned short* orow[4];
#pragma unroll
  for (int mo = 0; mo < 4; ++mo)
    orow[mo] = wot + ((size_t)(4 * wv + mo) << 13) + l15 * 8;

  // prologue: DMA ctx slice 0
#pragma unroll
  for (int p = 0; p < 2; ++p)
    gload_lds16(ctxn + p * 4096 + tid * 8, &sm[OXS + p * 8192 + (wv << 10)]);
  __syncthreads();

  for (int s = 0; s < 4; ++s) {
    if (s < 3) {
#pragma unroll
      for (int p = 0; p < 2; ++p)
        gload_lds16(ctxn + (size_t)(s + 1) * 8192 + p * 4096 + tid * 8,
                    &sm[OXS + ((s + 1) & 1) * 16384 + p * 8192 + (wv << 10)]);
    }
    const int cur = OXS + (s & 1) * 16384;
#pragma unroll
    for (int j = 0; j < 4; ++j) {
      const int c8g = 16 * s + 4 * j + qd;
      const int lb = cur + ((4 * j + qd) << 10);
      s16x8 bc[4];
#pragma unroll
      for (int ni = 0; ni < 4; ++ni)
        bc[ni] = *(const s16x8*)(&sm[lb + (16 * ni + l15) * 16]);
#pragma unroll
      for (int mo = 0; mo < 4; ++mo) {
        const s16x8 af = *(const s16x8*)(orow[mo] + ((size_t)c8g << 7));
#pragma unroll
        for (int ni = 0; ni < 4; ++ni)
          oacc[mo][ni] = __builtin_amdgcn_mfma_f32_16x16x32_bf16(af, bc[ni], oacc[mo][ni], 0, 0, 0);
      }
    }
    __syncthreads();
  }

#pragma unroll
  for (int mo = 0; mo < 4; ++mo) {
    const int od0 = 64 * wv + 16 * mo + 4 * qd;
    float bo[4];
#pragma unroll
    for (int i = 0; i < 4; ++i) bo[i] = bout[od0 + i];
#pragma unroll
    for (int ni = 0; ni < 4; ++ni) {
      const int tok = 16 * ni + l15;
      const int r = tok >> 3, cc = tok & 7;
#pragma unroll
      for (int i = 0; i < 4; ++i) {
        out[wbase + (size_t)(od0 + i) * CH_STRIDE + (size_t)r * HWIMG + cc] =
            oacc[mo][ni][i] + bo[i];
      }
    }
  }
}

// ======================= R3 fused fallback =======================
#define QO    0
#define KO    16384
#define VO    32768
#define PO    49152
#define CTXO  57344
#define LDSB  73728

__global__ void __launch_bounds__(256)
pack_x_fb(const float* __restrict__ x, unsigned short* __restrict__ xw) {
  const int n  = blockIdx.x;
  const int bb = n >> 8, hw = (n >> 4) & 15, ww = n & 15;
  const size_t wbase = (size_t)bb * C_TOT * CH_STRIDE
                     + (size_t)(hw * 8) * HWIMG + (size_t)(ww * 8);
  const int tok = threadIdx.x & 63;
  const int q4  = threadIdx.x >> 6;
  const int r = tok >> 3, cc = tok & 7;
  const float* px = x + wbase + (size_t)r * HWIMG + cc;
  unsigned short* pw = xw + (size_t)n * 32768;
#pragma unroll 4
  for (int j = 0; j < 16; ++j) {
    const int o = q4 * 16 + j;
    float v[8];
#pragma unroll
    for (int k = 0; k < 8; ++k) v[k] = px[(size_t)(8 * o + k) * CH_STRIDE];
    s16x8 pk;
#pragma unroll
    for (int k = 0; k < 8; ++k) pk[k] = (short)f2bf(v[k]);
    *(s16x8*)(pw + ((size_t)o * 64 + tok) * 8) = pk;
  }
}

__global__ void __launch_bounds__(512, 2)
local_attn_kernel(const unsigned short* __restrict__ xw,
                  const float* __restrict__ bin,
                  const float* __restrict__ bout,
                  const unsigned short* __restrict__ wi,
                  const unsigned short* __restrict__ wo,
                  float* __restrict__ out) {
  __shared__ __align__(16) unsigned char sm[LDSB];
  const int tid  = threadIdx.x;
  const int wv   = tid >> 6;
  const int lane = tid & 63;
  const int l15  = lane & 15;
  const int qd   = lane >> 4;
  const int swA  = (l15 & 7) << 4;
  const int n  = blockIdx.x;
  const int bb = n >> 8;
  const int hw = (n >> 4) & 15;
  const int ww = n & 15;
  const size_t wbase = (size_t)bb * C_TOT * CH_STRIDE
                     + (size_t)(hw * 8) * HWIMG + (size_t)(ww * 8);
  const unsigned short* xww = xw + (size_t)n * 32768;
  f32x4 oacc[4][4];
#pragma unroll
  for (int a = 0; a < 4; ++a)
#pragma unroll
    for (int b2 = 0; b2 < 4; ++b2) oacc[a][b2] = (f32x4){0.f, 0.f, 0.f, 0.f};
  const float SCALE = 0.08838834764831845f;
  const float L2E   = 1.4426950408889634f;
  for (int h = 0; h < 4; ++h) {
    f32x4 acc[3][4];
#pragma unroll
    for (int a = 0; a < 3; ++a)
#pragma unroll
      for (int b2 = 0; b2 < 4; ++b2) acc[a][b2] = (f32x4){0.f, 0.f, 0.f, 0.f};
    const unsigned short* arow[3];
    int typ[3], d128s[3];
#pragma unroll
    for (int mi = 0; mi < 3; ++mi) {
      const int d0 = 48 * wv + 16 * mi;
      const int t = d0 >> 7;
      const int d128 = d0 & 127;
      typ[mi] = t; d128s[mi] = d128;
      arow[mi] = wi + (size_t)(t * 512 + h * 128 + d128 + l15) * 512;
    }
#pragma unroll 4
    for (int ks = 0; ks < 16; ++ks) {
      const int c0 = 32 * ks + 8 * qd;
      const int c8 = c0 >> 3;
      s16x8 bx[4];
#pragma unroll
      for (int ni = 0; ni < 4; ++ni)
        bx[ni] = *(const s16x8*)(xww + ((size_t)c8 * 64 + 16 * ni + l15) * 8);
#pragma unroll
      for (int mi = 0; mi < 3; ++mi) {
        const s16x8 af = *(const s16x8*)(arow[mi] + c0);
#pragma unroll
        for (int ni = 0; ni < 4; ++ni)
          acc[mi][ni] = __builtin_amdgcn_mfma_f32_16x16x32_bf16(af, bx[ni], acc[mi][ni], 0, 0, 0);
      }
    }
#pragma unroll
    for (int mi = 0; mi < 3; ++mi) {
      const int t = typ[mi], d128 = d128s[mi];
      const int e0 = t * 512 + h * 128 + d128 + 4 * qd;
      const float bi0 = bin[e0], bi1 = bin[e0 + 1], bi2 = bin[e0 + 2], bi3 = bin[e0 + 3];
#pragma unroll
      for (int ni = 0; ni < 4; ++ni) {
        const int tok = 16 * ni + l15;
        const unsigned short h0 = f2bf(acc[mi][ni][0] + bi0);
        const unsigned short h1 = f2bf(acc[mi][ni][1] + bi1);
        const unsigned short h2 = f2bf(acc[mi][ni][2] + bi2);
        const unsigned short h3 = f2bf(acc[mi][ni][3] + bi3);
        if (t < 2) {
          const unsigned lo = (unsigned)h0 | ((unsigned)h1 << 16);
          const unsigned hi = (unsigned)h2 | ((unsigned)h3 << 16);
          const unsigned long long pk = (unsigned long long)lo | ((unsigned long long)hi << 32);
          const int base = (t == 0) ? QO : KO;
          *(unsigned long long*)(&sm[base + tok * 256 + ((2 * (d128 + 4 * qd)) ^ swA)]) = pk;
        } else {
          const int vd = d128 + 4 * qd;
          *(unsigned short*)(&sm[VO + (vd    ) * 128 + ((2 * tok) ^ (((vd    ) & 7) << 4))]) = h0;
          *(unsigned short*)(&sm[VO + (vd + 1) * 128 + ((2 * tok) ^ (((vd + 1) & 7) << 4))]) = h1;
          *(unsigned short*)(&sm[VO + (vd + 2) * 128 + ((2 * tok) ^ (((vd + 2) & 7) << 4))]) = h2;
          *(unsigned short*)(&sm[VO + (vd + 3) * 128 + ((2 * tok) ^ (((vd + 3) & 7) << 4))]) = h3;
        }
      }
    }
    __syncthreads();
    if (wv < 4) {
      f32x4 s[4];
#pragma unroll
      for (int a = 0; a < 4; ++a) s[a] = (f32x4){0.f, 0.f, 0.f, 0.f};
      const int tqa = 16 * wv + l15;
#pragma unroll
      for (int ks = 0; ks < 4; ++ks) {
        const int c0 = 32 * ks + 8 * qd;
        const s16x8 aq = *(const s16x8*)(&sm[QO + tqa * 256 + ((2 * c0) ^ swA)]);
#pragma unroll
        for (int ni = 0; ni < 4; ++ni) {
          const int tk = 16 * ni + l15;
          const s16x8 bk = *(const s16x8*)(&sm[KO + tk * 256 + ((2 * c0) ^ swA)]);
          s[ni] = __builtin_amdgcn_mfma_f32_16x16x32_bf16(aq, bk, s[ni], 0, 0, 0);
        }
      }
      float sv[4][4];
#pragma unroll
      for (int ni = 0; ni < 4; ++ni)
#pragma unroll
        for (int i = 0; i < 4; ++i) sv[ni][i] = s[ni][i] * SCALE;
      float m[4];
#pragma unroll
      for (int i = 0; i < 4; ++i)
        m[i] = fmaxf(fmaxf(sv[0][i], sv[1][i]), fmaxf(sv[2][i], sv[3][i]));
#pragma unroll
      for (int d = 1; d < 16; d <<= 1)
#pragma unroll
        for (int i = 0; i < 4; ++i) m[i] = fmaxf(m[i], __shfl_xor(m[i], d));
      float p[4][4], sum[4] = {0.f, 0.f, 0.f, 0.f};
#pragma unroll
      for (int ni = 0; ni < 4; ++ni)
#pragma unroll
        for (int i = 0; i < 4; ++i) {
          p[ni][i] = exp2f((sv[ni][i] - m[i]) * L2E);
          sum[i] += p[ni][i];
        }
#pragma unroll
      for (int d = 1; d < 16; d <<= 1)
#pragma unroll
        for (int i = 0; i < 4; ++i) sum[i] += __shfl_xor(sum[i], d);
      float rinv[4];
#pragma unroll
      for (int i = 0; i < 4; ++i) rinv[i] = 1.0f / sum[i];
#pragma unroll
      for (int ni = 0; ni < 4; ++ni)
#pragma unroll
        for (int i = 0; i < 4; ++i) {
          const int tqr = 16 * wv + 4 * qd + i;
          const int tk = 16 * ni + l15;
          *(unsigned short*)(&sm[PO + tqr * 128 + ((2 * tk) ^ ((tqr & 7) << 4))]) =
              f2bf(p[ni][i] * rinv[i]);
        }
    }
    __syncthreads();
    {
      const int mq = wv >> 1;
      const int nb = (wv & 1) * 4;
      f32x4 cacc[4];
#pragma unroll
      for (int a = 0; a < 4; ++a) cacc[a] = (f32x4){0.f, 0.f, 0.f, 0.f};
      const int tqa = 16 * mq + l15;
#pragma unroll
      for (int ks = 0; ks < 2; ++ks) {
        const int c0 = 32 * ks + 8 * qd;
        const s16x8 ap = *(const s16x8*)(&sm[PO + tqa * 128 + ((2 * c0) ^ swA)]);
#pragma unroll
        for (int j = 0; j < 4; ++j) {
          const int vda = 16 * (nb + j) + l15;
          const s16x8 bv = *(const s16x8*)(&sm[VO + vda * 128 + ((2 * c0) ^ swA)]);
          cacc[j] = __builtin_amdgcn_mfma_f32_16x16x32_bf16(ap, bv, cacc[j], 0, 0, 0);
        }
      }
#pragma unroll
      for (int j = 0; j < 4; ++j)
#pragma unroll
        for (int i = 0; i < 4; ++i) {
          const int tq = 16 * mq + 4 * qd + i;
          const int vd = 16 * (nb + j) + l15;
          *(unsigned short*)(&sm[CTXO + tq * 256 + ((2 * vd) ^ ((tq & 7) << 4))]) =
              f2bf(cacc[j][i]);
        }
    }
    __syncthreads();
    {
#pragma unroll
      for (int ks = 0; ks < 4; ++ks) {
        const int c0 = 32 * ks + 8 * qd;
        s16x8 a2[4];
#pragma unroll
        for (int mo = 0; mo < 4; ++mo) {
          const int od = 64 * wv + 16 * mo + l15;
          a2[mo] = *(const s16x8*)(&wo[(size_t)od * 512 + 128 * h + c0]);
        }
        s16x8 bc[4];
#pragma unroll
        for (int ni = 0; ni < 4; ++ni) {
          const int tok = 16 * ni + l15;
          bc[ni] = *(const s16x8*)(&sm[CTXO + tok * 256 + ((2 * c0) ^ swA)]);
        }
#pragma unroll
        for (int mo = 0; mo < 4; ++mo)
#pragma unroll
          for (int ni = 0; ni < 4; ++ni)
            oacc[mo][ni] = __builtin_amdgcn_mfma_f32_16x16x32_bf16(a2[mo], bc[ni], oacc[mo][ni], 0, 0, 0);
      }
    }
  }
#pragma unroll
  for (int mo = 0; mo < 4; ++mo) {
    const int od0 = 64 * wv + 16 * mo + 4 * qd;
    float bo[4];
#pragma unroll
    for (int i = 0; i < 4; ++i) bo[i] = bout[od0 + i];
#pragma unroll
    for (int ni = 0; ni < 4; ++ni) {
      const int tok = 16 * ni + l15;
      const int r = tok >> 3, cc = tok & 7;
#pragma unroll
      for (int i = 0; i < 4; ++i) {
        out[wbase + (size_t)(od0 + i) * CH_STRIDE + (size_t)r * HWIMG + cc] =
            oacc[mo][ni][i] + bo[i];
      }
    }
  }
}

extern "C" void kernel_launch(void* const* d_in, const int* in_sizes, int n_in,
                              void* d_out, int out_size, void* d_ws, size_t ws_size,
                              hipStream_t stream) {
  const float* x     = (const float*)d_in[0];
  const float* w_in  = (const float*)d_in[1];
  const float* b_in  = (const float*)d_in[2];
  const float* w_out = (const float*)d_in[3];
  const float* b_out = (const float*)d_in[4];
  float* out = (float*)d_out;

  const size_t TIL_BYTES = (WIT_ELEMS + WOT_ELEMS) * 2ull;   // 2MB
  // prefer nc=4 (ctx chunk 33.5MB ~ L2-resident); fall back to larger nc
  int nc = 0;
  for (int c = 4; c <= 8; c <<= 1) {
    if (ws_size >= XW_BYTES + TIL_BYTES + CTX_BYTES_FULL / (size_t)c) { nc = c; break; }
  }

  if (nc) {
    unsigned short* xwp = (unsigned short*)d_ws;
    unsigned short* wit = xwp + XW_ELEMS;
    unsigned short* wot = wit + WIT_ELEMS;
    unsigned short* ctx = wot + WOT_ELEMS;
    conv_wt_kernel<<<4096, 256, 0, stream>>>(w_in, w_out, wit, wot);
    pack_x_kernel<<<2048, 256, 0, stream>>>(x, xwp);
    const int nwc = NWIN / nc;
    for (int k = 0; k < nc; ++k) {
      qkv_attn_kernel<<<nwc * 4, 512, 0, stream>>>(xwp, b_in, wit, ctx, k * nwc);
      outproj_kernel<<<nwc, 512, 0, stream>>>(ctx, wot, b_out, out, k * nwc);
    }
  } else {
    // R3 fused fallback (requires ws >= 137MB, proven available)
    unsigned short* xwp = (unsigned short*)d_ws;
    unsigned short* wbf = xwp + XW_ELEMS;
    conv_w_kernel<<<4096, 256, 0, stream>>>(w_in, w_out, wbf);
    pack_x_fb<<<NWIN, 256, 0, stream>>>(x, xwp);
    local_attn_kernel<<<NWIN, 512, 0, stream>>>(xwp, b_in, b_out,
                                                wbf, wbf + 786432, out);
  }
}

// Round 10
// 631.142 us; speedup vs baseline: 1.0798x; 1.0798x over previous
//
#include <hip/hip_runtime.h>

// LocalAttention: windowed MHA. B=8, C=512, H=W=128, WS=8
// -> N=2048 windows x L=64 tokens, NH=4, hd=128.
//
// Main path:
//   conv_wt:  w_in/w_out f32 -> bf16 FRAGMENT-TILED
//   pack_x:   x f32 -> bf16 fragment-tiled xw[n][c8][tok][8], coalesced
//   qkv_attn: one block per (window, head), XCD-swizzled; QKV GEMM
//             (xw DMA-staged, tiled weights, balanced wave->tile map),
//             softmax, PV -> ctx in ws (single chunk, nc=1 preferred).
//   outproj:  GEMM out = w_out * ctx^T + b_out -> NCHW f32.
// Fallback: R3 fused kernel (plain weights).

typedef __attribute__((ext_vector_type(8))) short s16x8;   // 8 bf16
typedef __attribute__((ext_vector_type(4))) float f32x4;   // MFMA C/D

#define C_TOT 512
#define HWIMG 128
#define CH_STRIDE (HWIMG * HWIMG) /* 16384 */
#define NWIN 2048
#define XW_ELEMS ((size_t)NWIN * 64 * 512)     /* 67,108,864 bf16 */
#define XW_BYTES (XW_ELEMS * 2ull)             /* 134,217,728 B  */
#define WIT_ELEMS 786432ull                    /* tiled w_in  */
#define WOT_ELEMS 262144ull                    /* tiled w_out */
#define WBF_ELEMS 1048576ull
#define CTX_BYTES_FULL (XW_ELEMS * 2ull)       /* 134MB */

__device__ __forceinline__ unsigned short f2bf(float f) {
  unsigned u = __float_as_uint(f);
  u += 0x7FFFu + ((u >> 16) & 1u);       // RNE
  return (unsigned short)(u >> 16);
}

__device__ __forceinline__ unsigned cvt_pk_bf16(float a, float b) {
  unsigned r;
  asm("v_cvt_pk_bf16_f32 %0, %1, %2" : "=v"(r) : "v"(a), "v"(b));
  return r;   // lo = bf16(a), hi = bf16(b)
}

// async global->LDS DMA, 16B per lane; LDS dest = wave-uniform base + lane*16
__device__ __forceinline__ void gload_lds16(const void* g, void* l) {
  __builtin_amdgcn_global_load_lds(
      (const __attribute__((address_space(1))) unsigned int*)g,
      (__attribute__((address_space(3))) unsigned int*)l, 16, 0, 0);
}

// plain bf16 conversion (fallback path only)
__global__ void conv_w_kernel(const float* __restrict__ w_in,
                              const float* __restrict__ w_out,
                              unsigned short* __restrict__ wbf) {
  int i = blockIdx.x * blockDim.x + threadIdx.x;   // grid covers 1048576
  const int NIN = 3 * C_TOT * C_TOT;               // 786432
  float v = (i < NIN) ? w_in[i] : w_out[i - NIN];
  wbf[i] = f2bf(v);
}

// fragment-tiled weights:
//  wit[h4][m24][c8 64][l15 16][e8]: row = t*512 + h*128 + 16*(m%8) + l15
//  wot[m32][c8 64][l15 16][e8]:     row od = 16m + l15, chan = 8*c8+e
__global__ void conv_wt_kernel(const float* __restrict__ w_in,
                               const float* __restrict__ w_out,
                               unsigned short* __restrict__ wit,
                               unsigned short* __restrict__ wot) {
  int i = blockIdx.x * blockDim.x + threadIdx.x;   // 0..1048575
  const int NIN = 3 * C_TOT * C_TOT;               // 786432
  if (i < NIN) {
    const int e = i >> 9, c = i & 511;
    const int t = e >> 9, rem = e & 511;
    const int h = rem >> 7, d = rem & 127;
    const int m = t * 8 + (d >> 4), l = d & 15;
    const int c8 = c >> 3, ec = c & 7;
    wit[(((size_t)(h * 24 + m) * 64 + c8) << 7) + l * 8 + ec] = f2bf(w_in[i]);
  } else {
    const int j = i - NIN;                         // 0..262143
    const int od = j >> 9, c = j & 511;
    const int m = od >> 4, l = od & 15;
    const int c8 = c >> 3, ec = c & 7;
    wot[(((size_t)m * 64 + c8) << 7) + l * 8 + ec] = f2bf(w_out[j]);
  }
}

// pack_x: fully-coalesced float4 reads + in-register transpose.
__global__ void __launch_bounds__(256)
pack_x_kernel(const float* __restrict__ x, unsigned short* __restrict__ xw) {
  const int blk = blockIdx.x;
  const int bb  = blk >> 8;
  const int hw  = (blk >> 4) & 15;
  const int og4 = blk & 15;
  const int t   = threadIdx.x;
  const int p0  = 4 * t;                 // pixel in strip [0,1024)
  const int r   = p0 >> 7;               // row in window  [0,8)
  const int col0 = p0 & 127;             // col in strip   [0,128)
  const int n   = bb * 256 + hw * 16 + (col0 >> 3);
  const int tok0 = r * 8 + (col0 & 7);
  const float* xs = x + (size_t)bb * C_TOT * CH_STRIDE
                  + (size_t)hw * 1024 + p0;
  unsigned short* pw = xw + (size_t)n * 32768;
#pragma unroll
  for (int jo = 0; jo < 4; ++jo) {
    const int o = og4 * 4 + jo;          // channel octet 0..63
    float4 f[8];
#pragma unroll
    for (int k = 0; k < 8; ++k)
      f[k] = *(const float4*)(xs + (size_t)(8 * o + k) * CH_STRIDE);
#pragma unroll
    for (int i = 0; i < 4; ++i) {
      s16x8 pk;
      if (i == 0) {
        pk[0]=(short)f2bf(f[0].x); pk[1]=(short)f2bf(f[1].x); pk[2]=(short)f2bf(f[2].x); pk[3]=(short)f2bf(f[3].x);
        pk[4]=(short)f2bf(f[4].x); pk[5]=(short)f2bf(f[5].x); pk[6]=(short)f2bf(f[6].x); pk[7]=(short)f2bf(f[7].x);
      } else if (i == 1) {
        pk[0]=(short)f2bf(f[0].y); pk[1]=(short)f2bf(f[1].y); pk[2]=(short)f2bf(f[2].y); pk[3]=(short)f2bf(f[3].y);
        pk[4]=(short)f2bf(f[4].y); pk[5]=(short)f2bf(f[5].y); pk[6]=(short)f2bf(f[6].y); pk[7]=(short)f2bf(f[7].y);
      } else if (i == 2) {
        pk[0]=(short)f2bf(f[0].z); pk[1]=(short)f2bf(f[1].z); pk[2]=(short)f2bf(f[2].z); pk[3]=(short)f2bf(f[3].z);
        pk[4]=(short)f2bf(f[4].z); pk[5]=(short)f2bf(f[5].z); pk[6]=(short)f2bf(f[6].z); pk[7]=(short)f2bf(f[7].z);
      } else {
        pk[0]=(short)f2bf(f[0].w); pk[1]=(short)f2bf(f[1].w); pk[2]=(short)f2bf(f[2].w); pk[3]=(short)f2bf(f[3].w);
        pk[4]=(short)f2bf(f[4].w); pk[5]=(short)f2bf(f[5].w); pk[6]=(short)f2bf(f[6].w); pk[7]=(short)f2bf(f[7].w);
      }
      *(s16x8*)(pw + ((size_t)o * 64 + tok0 + i) * 8) = pk;
    }
  }
}

// ---- kernel B LDS layout (80KB) ----
#define BQO 0        // Q [tok 64][d 128] bf16, row 256B, swz ((tok&7)<<4)
#define BKO 16384
#define BVO 32768    // V^T [d 128][tok 64] bf16, row 128B, swz ((d&7)<<4)
#define BXS 49152    // xw slice dbuf: 2 x 16KB (K=128 slices, tiled linear)
#define BPO 49152    // P [tq 64][tk 64] bf16 normalized - OVERLAYS stage buf0
#define BLDS 81920

__global__ void __launch_bounds__(512, 4)
qkv_attn_kernel(const unsigned short* __restrict__ xw,   // tiled bf16 x
                const float* __restrict__ bin,
                const unsigned short* __restrict__ wit,  // tiled w_in bf16
                unsigned short* __restrict__ ctx,        // chunk base, tiled
                int n0) {
  __shared__ __align__(16) unsigned char sm[BLDS];

  const int tid  = threadIdx.x;
  const int wv   = tid >> 6;      // wave 0..7
  const int lane = tid & 63;
  const int l15  = lane & 15;
  const int qd   = lane >> 4;
  const int swA  = (l15 & 7) << 4;

  // XCD swizzle: blk = 32k + 8h + g -> window wrel = 8k + g, head h.
  const int blk = blockIdx.x;
  const int g   = blk & 7;
  const int q   = blk >> 3;
  const int h   = q & 3;
  const int nrel = (q >> 2) * 8 + g;
  const unsigned short* xww = xw + (size_t)(n0 + nrel) * 32768;

  const float SCALE = 0.08838834764831845f;  // 1/sqrt(128)
  const float L2E   = 1.4426950408889634f;

  // ====== QKV: balanced map — wave wv owns tiles {wv, wv+8, wv+16} ======
  f32x4 acc[3][4];
#pragma unroll
  for (int a = 0; a < 3; ++a)
#pragma unroll
    for (int b2 = 0; b2 < 4; ++b2) acc[a][b2] = (f32x4){0.f, 0.f, 0.f, 0.f};

  const int d128 = 16 * wv;
  const unsigned short* arow[3];
#pragma unroll
  for (int mi = 0; mi < 3; ++mi)
    arow[mi] = wit + ((size_t)(h * 24 + wv + 8 * mi) << 13) + l15 * 8;

  // prologue: DMA slice 0 (2 passes x 8KB)
#pragma unroll
  for (int p = 0; p < 2; ++p)
    gload_lds16(xww + p * 4096 + tid * 8, &sm[BXS + p * 8192 + (wv << 10)]);
  __syncthreads();

  for (int s = 0; s < 4; ++s) {
    if (s < 3) {
#pragma unroll
      for (int p = 0; p < 2; ++p)
        gload_lds16(xww + (size_t)(s + 1) * 8192 + p * 4096 + tid * 8,
                    &sm[BXS + ((s + 1) & 1) * 16384 + p * 8192 + (wv << 10)]);
    }
    const int cur = BXS + (s & 1) * 16384;
#pragma unroll
    for (int j = 0; j < 4; ++j) {
      const int c8g = 16 * s + 4 * j + qd;         // global channel octet
      const int lb = cur + ((4 * j + qd) << 10);   // local c8 block
      s16x8 bx[4];
#pragma unroll
      for (int ni = 0; ni < 4; ++ni)
        bx[ni] = *(const s16x8*)(&sm[lb + (16 * ni + l15) * 16]);
#pragma unroll
      for (int mi = 0; mi < 3; ++mi) {
        const s16x8 af = *(const s16x8*)(arow[mi] + ((size_t)c8g << 7));
#pragma unroll
        for (int ni = 0; ni < 4; ++ni)
          acc[mi][ni] = __builtin_amdgcn_mfma_f32_16x16x32_bf16(af, bx[ni], acc[mi][ni], 0, 0, 0);
      }
    }
    __syncthreads();   // drains vmcnt (DMA done) + all reads of cur complete
  }

  // epilogue: Q/K -> [tok][d] packed b64 (cvt_pk); V -> [d][tok] b16 scatter
#pragma unroll
  for (int mi = 0; mi < 3; ++mi) {
    const int e0 = mi * 512 + h * 128 + d128 + 4 * qd;
    const float bi0 = bin[e0], bi1 = bin[e0 + 1], bi2 = bin[e0 + 2], bi3 = bin[e0 + 3];
#pragma unroll
    for (int ni = 0; ni < 4; ++ni) {
      const int tok = 16 * ni + l15;
      if (mi < 2) {
        const unsigned lo = cvt_pk_bf16(acc[mi][ni][0] + bi0, acc[mi][ni][1] + bi1);
        const unsigned hi = cvt_pk_bf16(acc[mi][ni][2] + bi2, acc[mi][ni][3] + bi3);
        const unsigned long long pk = (unsigned long long)lo | ((unsigned long long)hi << 32);
        const int base = (mi == 0) ? BQO : BKO;
        *(unsigned long long*)(&sm[base + tok * 256 + ((2 * (d128 + 4 * qd)) ^ swA)]) = pk;
      } else {
        const unsigned short h0 = f2bf(acc[mi][ni][0] + bi0);
        const unsigned short h1 = f2bf(acc[mi][ni][1] + bi1);
        const unsigned short h2 = f2bf(acc[mi][ni][2] + bi2);
        const unsigned short h3 = f2bf(acc[mi][ni][3] + bi3);
        const int vd = d128 + 4 * qd;
        *(unsigned short*)(&sm[BVO + (vd    ) * 128 + ((2 * tok) ^ (((vd    ) & 7) << 4))]) = h0;
        *(unsigned short*)(&sm[BVO + (vd + 1) * 128 + ((2 * tok) ^ (((vd + 1) & 7) << 4))]) = h1;
        *(unsigned short*)(&sm[BVO + (vd + 2) * 128 + ((2 * tok) ^ (((vd + 2) & 7) << 4))]) = h2;
        *(unsigned short*)(&sm[BVO + (vd + 3) * 128 + ((2 * tok) ^ (((vd + 3) & 7) << 4))]) = h3;
      }
    }
  }
  __syncthreads();

  // ====== S = Q K^T, softmax (waves 0..3 own full rows), normalized P ======
  if (wv < 4) {
    f32x4 s[4];
#pragma unroll
    for (int a = 0; a < 4; ++a) s[a] = (f32x4){0.f, 0.f, 0.f, 0.f};
    const int tqa = 16 * wv + l15;
#pragma unroll
    for (int ks = 0; ks < 4; ++ks) {
      const int c0 = 32 * ks + 8 * qd;
      const s16x8 aq = *(const s16x8*)(&sm[BQO + tqa * 256 + ((2 * c0) ^ swA)]);
#pragma unroll
      for (int ni = 0; ni < 4; ++ni) {
        const int tk = 16 * ni + l15;
        const s16x8 bk = *(const s16x8*)(&sm[BKO + tk * 256 + ((2 * c0) ^ swA)]);
        s[ni] = __builtin_amdgcn_mfma_f32_16x16x32_bf16(aq, bk, s[ni], 0, 0, 0);
      }
    }
    float sv[4][4];
#pragma unroll
    for (int ni = 0; ni < 4; ++ni)
#pragma unroll
      for (int i = 0; i < 4; ++i) sv[ni][i] = s[ni][i] * SCALE;
    float m[4];
#pragma unroll
    for (int i = 0; i < 4; ++i)
      m[i] = fmaxf(fmaxf(sv[0][i], sv[1][i]), fmaxf(sv[2][i], sv[3][i]));
#pragma unroll
    for (int d = 1; d < 16; d <<= 1)
#pragma unroll
      for (int i = 0; i < 4; ++i) m[i] = fmaxf(m[i], __shfl_xor(m[i], d));
    float p[4][4], sum[4] = {0.f, 0.f, 0.f, 0.f};
#pragma unroll
    for (int ni = 0; ni < 4; ++ni)
#pragma unroll
      for (int i = 0; i < 4; ++i) {
        p[ni][i] = exp2f((sv[ni][i] - m[i]) * L2E);
        sum[i] += p[ni][i];
      }
#pragma unroll
    for (int d = 1; d < 16; d <<= 1)
#pragma unroll
      for (int i = 0; i < 4; ++i) sum[i] += __shfl_xor(sum[i], d);
    float rinv[4];
#pragma unroll
    for (int i = 0; i < 4; ++i) rinv[i] = 1.0f / sum[i];
#pragma unroll
    for (int ni = 0; ni < 4; ++ni)
#pragma unroll
      for (int i = 0; i < 4; ++i) {
        const int tqr = 16 * wv + 4 * qd + i;
        const int tk = 16 * ni + l15;
        *(unsigned short*)(&sm[BPO + tqr * 128 + ((2 * tk) ^ ((tqr & 7) << 4))]) =
            f2bf(p[ni][i] * rinv[i]);
      }
  }
  __syncthreads();

  // ====== PV: ctx[tq][vd] = sum_tk P[tq][tk] V^T[vd][tk]; write global ======
  {
    const int mq = wv >> 1;              // tq tile
    const int nb = (wv & 1) * 4;         // vd tile base
    f32x4 cacc[4];
#pragma unroll
    for (int a = 0; a < 4; ++a) cacc[a] = (f32x4){0.f, 0.f, 0.f, 0.f};
    const int tqa = 16 * mq + l15;
#pragma unroll
    for (int ks = 0; ks < 2; ++ks) {
      const int c0 = 32 * ks + 8 * qd;
      const s16x8 ap = *(const s16x8*)(&sm[BPO + tqa * 128 + ((2 * c0) ^ swA)]);
#pragma unroll
      for (int j = 0; j < 4; ++j) {
        const int vda = 16 * (nb + j) + l15;
        const s16x8 bv = *(const s16x8*)(&sm[BVO + vda * 128 + ((2 * c0) ^ swA)]);
        cacc[j] = __builtin_amdgcn_mfma_f32_16x16x32_bf16(ap, bv, cacc[j], 0, 0, 0);
      }
    }
    unsigned short* ctxn = ctx + (size_t)nrel * 32768;
#pragma unroll
    for (int j = 0; j < 4; ++j) {
      const int vd = 16 * (nb + j) + l15;
      const int c  = h * 128 + vd;
      const int c8 = c >> 3, e = c & 7;
#pragma unroll
      for (int i = 0; i < 4; ++i) {
        const int tq = 16 * mq + 4 * qd + i;
        ctxn[((size_t)c8 * 64 + tq) * 8 + e] = f2bf(cacc[j][i]);
      }
    }
  }
}

// ====== out-proj: out[od][tok] = sum_c wo[od][c]*ctx[tok][c] + b, NCHW ======
#define OXS 0        // ctx slice dbuf: 2 x 16KB
#define OLDS 32768

__global__ void __launch_bounds__(512, 4)
outproj_kernel(const unsigned short* __restrict__ ctx,   // chunk base, tiled
               const unsigned short* __restrict__ wot,   // tiled w_out bf16
               const float* __restrict__ bout,
               float* __restrict__ out, int n0) {
  __shared__ __align__(16) unsigned char sm[OLDS];

  const int tid  = threadIdx.x;
  const int wv   = tid >> 6;
  const int lane = tid & 63;
  const int l15  = lane & 15;
  const int qd   = lane >> 4;

  const int nrel = blockIdx.x;
  const int n  = n0 + nrel;
  const int bb = n >> 8, hw = (n >> 4) & 15, ww = n & 15;
  const size_t wbase = (size_t)bb * C_TOT * CH_STRIDE
                     + (size_t)(hw * 8) * HWIMG + (size_t)(ww * 8);
  const unsigned short* ctxn = ctx + (size_t)nrel * 32768;

  f32x4 oacc[4][4];
#pragma unroll
  for (int a = 0; a < 4; ++a)
#pragma unroll
    for (int b2 = 0; b2 < 4; ++b2) oacc[a][b2] = (f32x4){0.f, 0.f, 0.f, 0.f};

  const unsigned short* orow[4];
#pragma unroll
  for (int mo = 0; mo < 4; ++mo)
    orow[mo] = wot + ((size_t)(4 * wv + mo) << 13) + l15 * 8;

  // prologue: DMA ctx slice 0
#pragma unroll
  for (int p = 0; p < 2; ++p)
    gload_lds16(ctxn + p * 4096 + tid * 8, &sm[OXS + p * 8192 + (wv << 10)]);
  __syncthreads();

  for (int s = 0; s < 4; ++s) {
    if (s < 3) {
#pragma unroll
      for (int p = 0; p < 2; ++p)
        gload_lds16(ctxn + (size_t)(s + 1) * 8192 + p * 4096 + tid * 8,
                    &sm[OXS + ((s + 1) & 1) * 16384 + p * 8192 + (wv << 10)]);
    }
    const int cur = OXS + (s & 1) * 16384;
#pragma unroll
    for (int j = 0; j < 4; ++j) {
      const int c8g = 16 * s + 4 * j + qd;
      const int lb = cur + ((4 * j + qd) << 10);
      s16x8 bc[4];
#pragma unroll
      for (int ni = 0; ni < 4; ++ni)
        bc[ni] = *(const s16x8*)(&sm[lb + (16 * ni + l15) * 16]);
#pragma unroll
      for (int mo = 0; mo < 4; ++mo) {
        const s16x8 af = *(const s16x8*)(orow[mo] + ((size_t)c8g << 7));
#pragma unroll
        for (int ni = 0; ni < 4; ++ni)
          oacc[mo][ni] = __builtin_amdgcn_mfma_f32_16x16x32_bf16(af, bc[ni], oacc[mo][ni], 0, 0, 0);
      }
    }
    __syncthreads();
  }

#pragma unroll
  for (int mo = 0; mo < 4; ++mo) {
    const int od0 = 64 * wv + 16 * mo + 4 * qd;
    float bo[4];
#pragma unroll
    for (int i = 0; i < 4; ++i) bo[i] = bout[od0 + i];
#pragma unroll
    for (int ni = 0; ni < 4; ++ni) {
      const int tok = 16 * ni + l15;
      const int r = tok >> 3, cc = tok & 7;
#pragma unroll
      for (int i = 0; i < 4; ++i) {
        out[wbase + (size_t)(od0 + i) * CH_STRIDE + (size_t)r * HWIMG + cc] =
            oacc[mo][ni][i] + bo[i];
      }
    }
  }
}

// ======================= R3 fused fallback =======================
#define QO    0
#define KO    16384
#define VO    32768
#define PO    49152
#define CTXO  57344
#define LDSB  73728

__global__ void __launch_bounds__(256)
pack_x_fb(const float* __restrict__ x, unsigned short* __restrict__ xw) {
  const int n  = blockIdx.x;
  const int bb = n >> 8, hw = (n >> 4) & 15, ww = n & 15;
  const size_t wbase = (size_t)bb * C_TOT * CH_STRIDE
                     + (size_t)(hw * 8) * HWIMG + (size_t)(ww * 8);
  const int tok = threadIdx.x & 63;
  const int q4  = threadIdx.x >> 6;
  const int r = tok >> 3, cc = tok & 7;
  const float* px = x + wbase + (size_t)r * HWIMG + cc;
  unsigned short* pw = xw + (size_t)n * 32768;
#pragma unroll 4
  for (int j = 0; j < 16; ++j) {
    const int o = q4 * 16 + j;
    float v[8];
#pragma unroll
    for (int k = 0; k < 8; ++k) v[k] = px[(size_t)(8 * o + k) * CH_STRIDE];
    s16x8 pk;
#pragma unroll
    for (int k = 0; k < 8; ++k) pk[k] = (short)f2bf(v[k]);
    *(s16x8*)(pw + ((size_t)o * 64 + tok) * 8) = pk;
  }
}

__global__ void __launch_bounds__(512, 2)
local_attn_kernel(const unsigned short* __restrict__ xw,
                  const float* __restrict__ bin,
                  const float* __restrict__ bout,
                  const unsigned short* __restrict__ wi,
                  const unsigned short* __restrict__ wo,
                  float* __restrict__ out) {
  __shared__ __align__(16) unsigned char sm[LDSB];
  const int tid  = threadIdx.x;
  const int wv   = tid >> 6;
  const int lane = tid & 63;
  const int l15  = lane & 15;
  const int qd   = lane >> 4;
  const int swA  = (l15 & 7) << 4;
  const int n  = blockIdx.x;
  const int bb = n >> 8;
  const int hw = (n >> 4) & 15;
  const int ww = n & 15;
  const size_t wbase = (size_t)bb * C_TOT * CH_STRIDE
                     + (size_t)(hw * 8) * HWIMG + (size_t)(ww * 8);
  const unsigned short* xww = xw + (size_t)n * 32768;
  f32x4 oacc[4][4];
#pragma unroll
  for (int a = 0; a < 4; ++a)
#pragma unroll
    for (int b2 = 0; b2 < 4; ++b2) oacc[a][b2] = (f32x4){0.f, 0.f, 0.f, 0.f};
  const float SCALE = 0.08838834764831845f;
  const float L2E   = 1.4426950408889634f;
  for (int h = 0; h < 4; ++h) {
    f32x4 acc[3][4];
#pragma unroll
    for (int a = 0; a < 3; ++a)
#pragma unroll
      for (int b2 = 0; b2 < 4; ++b2) acc[a][b2] = (f32x4){0.f, 0.f, 0.f, 0.f};
    const unsigned short* arow[3];
    int typ[3], d128s[3];
#pragma unroll
    for (int mi = 0; mi < 3; ++mi) {
      const int d0 = 48 * wv + 16 * mi;
      const int t = d0 >> 7;
      const int d128 = d0 & 127;
      typ[mi] = t; d128s[mi] = d128;
      arow[mi] = wi + (size_t)(t * 512 + h * 128 + d128 + l15) * 512;
    }
#pragma unroll 4
    for (int ks = 0; ks < 16; ++ks) {
      const int c0 = 32 * ks + 8 * qd;
      const int c8 = c0 >> 3;
      s16x8 bx[4];
#pragma unroll
      for (int ni = 0; ni < 4; ++ni)
        bx[ni] = *(const s16x8*)(xww + ((size_t)c8 * 64 + 16 * ni + l15) * 8);
#pragma unroll
      for (int mi = 0; mi < 3; ++mi) {
        const s16x8 af = *(const s16x8*)(arow[mi] + c0);
#pragma unroll
        for (int ni = 0; ni < 4; ++ni)
          acc[mi][ni] = __builtin_amdgcn_mfma_f32_16x16x32_bf16(af, bx[ni], acc[mi][ni], 0, 0, 0);
      }
    }
#pragma unroll
    for (int mi = 0; mi < 3; ++mi) {
      const int t = typ[mi], d128 = d128s[mi];
      const int e0 = t * 512 + h * 128 + d128 + 4 * qd;
      const float bi0 = bin[e0], bi1 = bin[e0 + 1], bi2 = bin[e0 + 2], bi3 = bin[e0 + 3];
#pragma unroll
      for (int ni = 0; ni < 4; ++ni) {
        const int tok = 16 * ni + l15;
        const unsigned short h0 = f2bf(acc[mi][ni][0] + bi0);
        const unsigned short h1 = f2bf(acc[mi][ni][1] + bi1);
        const unsigned short h2 = f2bf(acc[mi][ni][2] + bi2);
        const unsigned short h3 = f2bf(acc[mi][ni][3] + bi3);
        if (t < 2) {
          const unsigned lo = (unsigned)h0 | ((unsigned)h1 << 16);
          const unsigned hi = (unsigned)h2 | ((unsigned)h3 << 16);
          const unsigned long long pk = (unsigned long long)lo | ((unsigned long long)hi << 32);
          const int base = (t == 0) ? QO : KO;
          *(unsigned long long*)(&sm[base + tok * 256 + ((2 * (d128 + 4 * qd)) ^ swA)]) = pk;
        } else {
          const int vd = d128 + 4 * qd;
          *(unsigned short*)(&sm[VO + (vd    ) * 128 + ((2 * tok) ^ (((vd    ) & 7) << 4))]) = h0;
          *(unsigned short*)(&sm[VO + (vd + 1) * 128 + ((2 * tok) ^ (((vd + 1) & 7) << 4))]) = h1;
          *(unsigned short*)(&sm[VO + (vd + 2) * 128 + ((2 * tok) ^ (((vd + 2) & 7) << 4))]) = h2;
          *(unsigned short*)(&sm[VO + (vd + 3) * 128 + ((2 * tok) ^ (((vd + 3) & 7) << 4))]) = h3;
        }
      }
    }
    __syncthreads();
    if (wv < 4) {
      f32x4 s[4];
#pragma unroll
      for (int a = 0; a < 4; ++a) s[a] = (f32x4){0.f, 0.f, 0.f, 0.f};
      const int tqa = 16 * wv + l15;
#pragma unroll
      for (int ks = 0; ks < 4; ++ks) {
        const int c0 = 32 * ks + 8 * qd;
        const s16x8 aq = *(const s16x8*)(&sm[QO + tqa * 256 + ((2 * c0) ^ swA)]);
#pragma unroll
        for (int ni = 0; ni < 4; ++ni) {
          const int tk = 16 * ni + l15;
          const s16x8 bk = *(const s16x8*)(&sm[KO + tk * 256 + ((2 * c0) ^ swA)]);
          s[ni] = __builtin_amdgcn_mfma_f32_16x16x32_bf16(aq, bk, s[ni], 0, 0, 0);
        }
      }
      float sv[4][4];
#pragma unroll
      for (int ni = 0; ni < 4; ++ni)
#pragma unroll
        for (int i = 0; i < 4; ++i) sv[ni][i] = s[ni][i] * SCALE;
      float m[4];
#pragma unroll
      for (int i = 0; i < 4; ++i)
        m[i] = fmaxf(fmaxf(sv[0][i], sv[1][i]), fmaxf(sv[2][i], sv[3][i]));
#pragma unroll
      for (int d = 1; d < 16; d <<= 1)
#pragma unroll
        for (int i = 0; i < 4; ++i) m[i] = fmaxf(m[i], __shfl_xor(m[i], d));
      float p[4][4], sum[4] = {0.f, 0.f, 0.f, 0.f};
#pragma unroll
      for (int ni = 0; ni < 4; ++ni)
#pragma unroll
        for (int i = 0; i < 4; ++i) {
          p[ni][i] = exp2f((sv[ni][i] - m[i]) * L2E);
          sum[i] += p[ni][i];
        }
#pragma unroll
      for (int d = 1; d < 16; d <<= 1)
#pragma unroll
        for (int i = 0; i < 4; ++i) sum[i] += __shfl_xor(sum[i], d);
      float rinv[4];
#pragma unroll
      for (int i = 0; i < 4; ++i) rinv[i] = 1.0f / sum[i];
#pragma unroll
      for (int ni = 0; ni < 4; ++ni)
#pragma unroll
        for (int i = 0; i < 4; ++i) {
          const int tqr = 16 * wv + 4 * qd + i;
          const int tk = 16 * ni + l15;
          *(unsigned short*)(&sm[PO + tqr * 128 + ((2 * tk) ^ ((tqr & 7) << 4))]) =
              f2bf(p[ni][i] * rinv[i]);
        }
    }
    __syncthreads();
    {
      const int mq = wv >> 1;
      const int nb = (wv & 1) * 4;
      f32x4 cacc[4];
#pragma unroll
      for (int a = 0; a < 4; ++a) cacc[a] = (f32x4){0.f, 0.f, 0.f, 0.f};
      const int tqa = 16 * mq + l15;
#pragma unroll
      for (int ks = 0; ks < 2; ++ks) {
        const int c0 = 32 * ks + 8 * qd;
        const s16x8 ap = *(const s16x8*)(&sm[PO + tqa * 128 + ((2 * c0) ^ swA)]);
#pragma unroll
        for (int j = 0; j < 4; ++j) {
          const int vda = 16 * (nb + j) + l15;
          const s16x8 bv = *(const s16x8*)(&sm[VO + vda * 128 + ((2 * c0) ^ swA)]);
          cacc[j] = __builtin_amdgcn_mfma_f32_16x16x32_bf16(ap, bv, cacc[j], 0, 0, 0);
        }
      }
#pragma unroll
      for (int j = 0; j < 4; ++j)
#pragma unroll
        for (int i = 0; i < 4; ++i) {
          const int tq = 16 * mq + 4 * qd + i;
          const int vd = 16 * (nb + j) + l15;
          *(unsigned short*)(&sm[CTXO + tq * 256 + ((2 * vd) ^ ((tq & 7) << 4))]) =
              f2bf(cacc[j][i]);
        }
    }
    __syncthreads();
    {
#pragma unroll
      for (int ks = 0; ks < 4; ++ks) {
        const int c0 = 32 * ks + 8 * qd;
        s16x8 a2[4];
#pragma unroll
        for (int mo = 0; mo < 4; ++mo) {
          const int od = 64 * wv + 16 * mo + l15;
          a2[mo] = *(const s16x8*)(&wo[(size_t)od * 512 + 128 * h + c0]);
        }
        s16x8 bc[4];
#pragma unroll
        for (int ni = 0; ni < 4; ++ni) {
          const int tok = 16 * ni + l15;
          bc[ni] = *(const s16x8*)(&sm[CTXO + tok * 256 + ((2 * c0) ^ swA)]);
        }
#pragma unroll
        for (int mo = 0; mo < 4; ++mo)
#pragma unroll
          for (int ni = 0; ni < 4; ++ni)
            oacc[mo][ni] = __builtin_amdgcn_mfma_f32_16x16x32_bf16(a2[mo], bc[ni], oacc[mo][ni], 0, 0, 0);
      }
    }
  }
#pragma unroll
  for (int mo = 0; mo < 4; ++mo) {
    const int od0 = 64 * wv + 16 * mo + 4 * qd;
    float bo[4];
#pragma unroll
    for (int i = 0; i < 4; ++i) bo[i] = bout[od0 + i];
#pragma unroll
    for (int ni = 0; ni < 4; ++ni) {
      const int tok = 16 * ni + l15;
      const int r = tok >> 3, cc = tok & 7;
#pragma unroll
      for (int i = 0; i < 4; ++i) {
        out[wbase + (size_t)(od0 + i) * CH_STRIDE + (size_t)r * HWIMG + cc] =
            oacc[mo][ni][i] + bo[i];
      }
    }
  }
}

extern "C" void kernel_launch(void* const* d_in, const int* in_sizes, int n_in,
                              void* d_out, int out_size, void* d_ws, size_t ws_size,
                              hipStream_t stream) {
  const float* x     = (const float*)d_in[0];
  const float* w_in  = (const float*)d_in[1];
  const float* b_in  = (const float*)d_in[2];
  const float* w_out = (const float*)d_in[3];
  const float* b_out = (const float*)d_in[4];
  float* out = (float*)d_out;

  const size_t TIL_BYTES = (WIT_ELEMS + WOT_ELEMS) * 2ull;   // 2MB
  // prefer nc=1 (single launch pair, no serialization boundaries)
  int nc = 0;
  for (int c = 1; c <= 8; c <<= 1) {
    if (ws_size >= XW_BYTES + TIL_BYTES + CTX_BYTES_FULL / (size_t)c) { nc = c; break; }
  }

  if (nc) {
    unsigned short* xwp = (unsigned short*)d_ws;
    unsigned short* wit = xwp + XW_ELEMS;
    unsigned short* wot = wit + WIT_ELEMS;
    unsigned short* ctx = wot + WOT_ELEMS;
    conv_wt_kernel<<<4096, 256, 0, stream>>>(w_in, w_out, wit, wot);
    pack_x_kernel<<<2048, 256, 0, stream>>>(x, xwp);
    const int nwc = NWIN / nc;
    for (int k = 0; k < nc; ++k) {
      qkv_attn_kernel<<<nwc * 4, 512, 0, stream>>>(xwp, b_in, wit, ctx, k * nwc);
      outproj_kernel<<<nwc, 512, 0, stream>>>(ctx, wot, b_out, out, k * nwc);
    }
  } else {
    // R3 fused fallback (requires ws >= 137MB, proven available)
    unsigned short* xwp = (unsigned short*)d_ws;
    unsigned short* wbf = xwp + XW_ELEMS;
    conv_w_kernel<<<4096, 256, 0, stream>>>(w_in, w_out, wbf);
    pack_x_fb<<<NWIN, 256, 0, stream>>>(x, xwp);
    local_attn_kernel<<<NWIN, 512, 0, stream>>>(xwp, b_in, b_out,
                                                wbf, wbf + 786432, out);
  }
}

// Round 11
// 585.462 us; speedup vs baseline: 1.1641x; 1.0780x over previous
//
#include <hip/hip_runtime.h>

// LocalAttention: windowed MHA. B=8, C=512, H=W=128, WS=8
// -> N=2048 windows x L=64 tokens, NH=4, hd=128.
//
// Main path:
//   conv_wt:  w_in/w_out f32 -> bf16 FRAGMENT-TILED
//   pack_x:   x f32 -> bf16 fragment-tiled xw[n][c8][tok][8], coalesced
//   qkv_attn: one block per (window, head), XCD-swizzled; QKV GEMM
//             (xw DMA-staged, tiled weights, R8-proven tile map),
//             8-wave S+softmax (S staged f32 in dead LDS), PV -> ctx in ws.
//   outproj:  GEMM out = w_out * ctx^T + b_out -> NCHW f32.
// Fallback: R3 fused kernel (plain weights).

typedef __attribute__((ext_vector_type(8))) short s16x8;   // 8 bf16
typedef __attribute__((ext_vector_type(4))) float f32x4;   // MFMA C/D

#define C_TOT 512
#define HWIMG 128
#define CH_STRIDE (HWIMG * HWIMG) /* 16384 */
#define NWIN 2048
#define XW_ELEMS ((size_t)NWIN * 64 * 512)     /* 67,108,864 bf16 */
#define XW_BYTES (XW_ELEMS * 2ull)             /* 134,217,728 B  */
#define WIT_ELEMS 786432ull                    /* tiled w_in  */
#define WOT_ELEMS 262144ull                    /* tiled w_out */
#define WBF_ELEMS 1048576ull
#define CTX_BYTES_FULL (XW_ELEMS * 2ull)       /* 134MB */

__device__ __forceinline__ unsigned short f2bf(float f) {
  unsigned u = __float_as_uint(f);
  u += 0x7FFFu + ((u >> 16) & 1u);       // RNE
  return (unsigned short)(u >> 16);
}

// async global->LDS DMA, 16B per lane; LDS dest = wave-uniform base + lane*16
__device__ __forceinline__ void gload_lds16(const void* g, void* l) {
  __builtin_amdgcn_global_load_lds(
      (const __attribute__((address_space(1))) unsigned int*)g,
      (__attribute__((address_space(3))) unsigned int*)l, 16, 0, 0);
}

// plain bf16 conversion (fallback path only)
__global__ void conv_w_kernel(const float* __restrict__ w_in,
                              const float* __restrict__ w_out,
                              unsigned short* __restrict__ wbf) {
  int i = blockIdx.x * blockDim.x + threadIdx.x;   // grid covers 1048576
  const int NIN = 3 * C_TOT * C_TOT;               // 786432
  float v = (i < NIN) ? w_in[i] : w_out[i - NIN];
  wbf[i] = f2bf(v);
}

// fragment-tiled weights:
//  wit[h4][m24][c8 64][l15 16][e8]: row = t*512 + h*128 + 16*(m%8) + l15
//  wot[m32][c8 64][l15 16][e8]:     row od = 16m + l15, chan = 8*c8+e
__global__ void conv_wt_kernel(const float* __restrict__ w_in,
                               const float* __restrict__ w_out,
                               unsigned short* __restrict__ wit,
                               unsigned short* __restrict__ wot) {
  int i = blockIdx.x * blockDim.x + threadIdx.x;   // 0..1048575
  const int NIN = 3 * C_TOT * C_TOT;               // 786432
  if (i < NIN) {
    const int e = i >> 9, c = i & 511;
    const int t = e >> 9, rem = e & 511;
    const int h = rem >> 7, d = rem & 127;
    const int m = t * 8 + (d >> 4), l = d & 15;
    const int c8 = c >> 3, ec = c & 7;
    wit[(((size_t)(h * 24 + m) * 64 + c8) << 7) + l * 8 + ec] = f2bf(w_in[i]);
  } else {
    const int j = i - NIN;                         // 0..262143
    const int od = j >> 9, c = j & 511;
    const int m = od >> 4, l = od & 15;
    const int c8 = c >> 3, ec = c & 7;
    wot[(((size_t)m * 64 + c8) << 7) + l * 8 + ec] = f2bf(w_out[j]);
  }
}

// pack_x: fully-coalesced float4 reads + in-register transpose.
__global__ void __launch_bounds__(256)
pack_x_kernel(const float* __restrict__ x, unsigned short* __restrict__ xw) {
  const int blk = blockIdx.x;
  const int bb  = blk >> 8;
  const int hw  = (blk >> 4) & 15;
  const int og4 = blk & 15;
  const int t   = threadIdx.x;
  const int p0  = 4 * t;                 // pixel in strip [0,1024)
  const int r   = p0 >> 7;               // row in window  [0,8)
  const int col0 = p0 & 127;             // col in strip   [0,128)
  const int n   = bb * 256 + hw * 16 + (col0 >> 3);
  const int tok0 = r * 8 + (col0 & 7);
  const float* xs = x + (size_t)bb * C_TOT * CH_STRIDE
                  + (size_t)hw * 1024 + p0;
  unsigned short* pw = xw + (size_t)n * 32768;
#pragma unroll
  for (int jo = 0; jo < 4; ++jo) {
    const int o = og4 * 4 + jo;          // channel octet 0..63
    float4 f[8];
#pragma unroll
    for (int k = 0; k < 8; ++k)
      f[k] = *(const float4*)(xs + (size_t)(8 * o + k) * CH_STRIDE);
#pragma unroll
    for (int i = 0; i < 4; ++i) {
      s16x8 pk;
      if (i == 0) {
        pk[0]=(short)f2bf(f[0].x); pk[1]=(short)f2bf(f[1].x); pk[2]=(short)f2bf(f[2].x); pk[3]=(short)f2bf(f[3].x);
        pk[4]=(short)f2bf(f[4].x); pk[5]=(short)f2bf(f[5].x); pk[6]=(short)f2bf(f[6].x); pk[7]=(short)f2bf(f[7].x);
      } else if (i == 1) {
        pk[0]=(short)f2bf(f[0].y); pk[1]=(short)f2bf(f[1].y); pk[2]=(short)f2bf(f[2].y); pk[3]=(short)f2bf(f[3].y);
        pk[4]=(short)f2bf(f[4].y); pk[5]=(short)f2bf(f[5].y); pk[6]=(short)f2bf(f[6].y); pk[7]=(short)f2bf(f[7].y);
      } else if (i == 2) {
        pk[0]=(short)f2bf(f[0].z); pk[1]=(short)f2bf(f[1].z); pk[2]=(short)f2bf(f[2].z); pk[3]=(short)f2bf(f[3].z);
        pk[4]=(short)f2bf(f[4].z); pk[5]=(short)f2bf(f[5].z); pk[6]=(short)f2bf(f[6].z); pk[7]=(short)f2bf(f[7].z);
      } else {
        pk[0]=(short)f2bf(f[0].w); pk[1]=(short)f2bf(f[1].w); pk[2]=(short)f2bf(f[2].w); pk[3]=(short)f2bf(f[3].w);
        pk[4]=(short)f2bf(f[4].w); pk[5]=(short)f2bf(f[5].w); pk[6]=(short)f2bf(f[6].w); pk[7]=(short)f2bf(f[7].w);
      }
      *(s16x8*)(pw + ((size_t)o * 64 + tok0 + i) * 8) = pk;
    }
  }
}

// ---- kernel B LDS layout (80KB) ----
#define BQO 0        // Q [tok 64][d 128] bf16, row 256B, swz ((tok&7)<<4)
#define BKO 16384
#define BVO 32768    // V^T [d 128][tok 64] bf16, row 128B, swz ((d&7)<<4)
#define BXS 49152    // xw slice dbuf: 2 x 16KB (dead after GEMM)
#define BPO 49152    // P [tq 64][tk 64] bf16 - OVERLAYS stage (dead)
#define BSO 57344    // S [tq 64][tk 64] f32, row 256B - OVERLAYS stage (dead)
#define BLDS 81920

__global__ void __launch_bounds__(512, 4)
qkv_attn_kernel(const unsigned short* __restrict__ xw,   // tiled bf16 x
                const float* __restrict__ bin,
                const unsigned short* __restrict__ wit,  // tiled w_in bf16
                unsigned short* __restrict__ ctx,        // chunk base, tiled
                int n0) {
  __shared__ __align__(16) unsigned char sm[BLDS];

  const int tid  = threadIdx.x;
  const int wv   = tid >> 6;      // wave 0..7
  const int lane = tid & 63;
  const int l15  = lane & 15;
  const int qd   = lane >> 4;
  const int swA  = (l15 & 7) << 4;

  // XCD swizzle: blk = 32k + 8h + g -> window wrel = 8k + g, head h.
  const int blk = blockIdx.x;
  const int g   = blk & 7;
  const int q   = blk >> 3;
  const int h   = q & 3;
  const int nrel = (q >> 2) * 8 + g;
  const unsigned short* xww = xw + (size_t)(n0 + nrel) * 32768;

  const float SCALE = 0.08838834764831845f;  // 1/sqrt(128)
  const float L2E   = 1.4426950408889634f;

  // ====== QKV GEMM: R8-proven map — wave wv owns dims [48wv, 48wv+48) ======
  f32x4 acc[3][4];
#pragma unroll
  for (int a = 0; a < 3; ++a)
#pragma unroll
    for (int b2 = 0; b2 < 4; ++b2) acc[a][b2] = (f32x4){0.f, 0.f, 0.f, 0.f};

  const unsigned short* arow[3];
  int typ[3], d128s[3];
#pragma unroll
  for (int mi = 0; mi < 3; ++mi) {
    const int d0 = 48 * wv + 16 * mi;     // dim base within QKV-384
    const int t = d0 >> 7;                // 0=Q 1=K 2=V
    const int d128 = d0 & 127;
    typ[mi] = t; d128s[mi] = d128;
    const int m = t * 8 + (d128 >> 4);    // tile index within head
    arow[mi] = wit + ((size_t)(h * 24 + m) << 13) + l15 * 8;
  }

  // prologue: DMA slice 0 (2 passes x 8KB)
#pragma unroll
  for (int p = 0; p < 2; ++p)
    gload_lds16(xww + p * 4096 + tid * 8, &sm[BXS + p * 8192 + (wv << 10)]);
  __syncthreads();

  for (int s = 0; s < 4; ++s) {
    if (s < 3) {
#pragma unroll
      for (int p = 0; p < 2; ++p)
        gload_lds16(xww + (size_t)(s + 1) * 8192 + p * 4096 + tid * 8,
                    &sm[BXS + ((s + 1) & 1) * 16384 + p * 8192 + (wv << 10)]);
    }
    const int cur = BXS + (s & 1) * 16384;
#pragma unroll
    for (int j = 0; j < 4; ++j) {
      const int c8g = 16 * s + 4 * j + qd;         // global channel octet
      const int lb = cur + ((4 * j + qd) << 10);   // local c8 block
      s16x8 bx[4];
#pragma unroll
      for (int ni = 0; ni < 4; ++ni)
        bx[ni] = *(const s16x8*)(&sm[lb + (16 * ni + l15) * 16]);
#pragma unroll
      for (int mi = 0; mi < 3; ++mi) {
        const s16x8 af = *(const s16x8*)(arow[mi] + ((size_t)c8g << 7));
#pragma unroll
        for (int ni = 0; ni < 4; ++ni)
          acc[mi][ni] = __builtin_amdgcn_mfma_f32_16x16x32_bf16(af, bx[ni], acc[mi][ni], 0, 0, 0);
      }
    }
    __syncthreads();   // drains vmcnt (DMA done) + all reads of cur complete
  }

  // epilogue (R8-proven): Q/K -> [tok][d] packed b64; V -> [d][tok] scatter
#pragma unroll
  for (int mi = 0; mi < 3; ++mi) {
    const int t = typ[mi], d128 = d128s[mi];
    const int e0 = t * 512 + h * 128 + d128 + 4 * qd;
    const float bi0 = bin[e0], bi1 = bin[e0 + 1], bi2 = bin[e0 + 2], bi3 = bin[e0 + 3];
#pragma unroll
    for (int ni = 0; ni < 4; ++ni) {
      const int tok = 16 * ni + l15;
      const unsigned short h0 = f2bf(acc[mi][ni][0] + bi0);
      const unsigned short h1 = f2bf(acc[mi][ni][1] + bi1);
      const unsigned short h2 = f2bf(acc[mi][ni][2] + bi2);
      const unsigned short h3 = f2bf(acc[mi][ni][3] + bi3);
      if (t < 2) {
        const unsigned lo = (unsigned)h0 | ((unsigned)h1 << 16);
        const unsigned hi = (unsigned)h2 | ((unsigned)h3 << 16);
        const unsigned long long pk = (unsigned long long)lo | ((unsigned long long)hi << 32);
        const int base = (t == 0) ? BQO : BKO;
        *(unsigned long long*)(&sm[base + tok * 256 + ((2 * (d128 + 4 * qd)) ^ swA)]) = pk;
      } else {
        const int vd = d128 + 4 * qd;
        *(unsigned short*)(&sm[BVO + (vd    ) * 128 + ((2 * tok) ^ (((vd    ) & 7) << 4))]) = h0;
        *(unsigned short*)(&sm[BVO + (vd + 1) * 128 + ((2 * tok) ^ (((vd + 1) & 7) << 4))]) = h1;
        *(unsigned short*)(&sm[BVO + (vd + 2) * 128 + ((2 * tok) ^ (((vd + 2) & 7) << 4))]) = h2;
        *(unsigned short*)(&sm[BVO + (vd + 3) * 128 + ((2 * tok) ^ (((vd + 3) & 7) << 4))]) = h3;
      }
    }
  }
  __syncthreads();

  // ====== Phase A: S = QK^T * scale -> f32 LDS; ALL 8 waves, 2 tiles each ==
  {
    const int mq  = wv >> 1;             // q-tile 0..3
    const int nk0 = (wv & 1) * 2;        // k-tile pair base
    f32x4 s[2];
#pragma unroll
    for (int a = 0; a < 2; ++a) s[a] = (f32x4){0.f, 0.f, 0.f, 0.f};
    const int tqa = 16 * mq + l15;
#pragma unroll
    for (int ks = 0; ks < 4; ++ks) {
      const int c0 = 32 * ks + 8 * qd;
      const s16x8 aq = *(const s16x8*)(&sm[BQO + tqa * 256 + ((2 * c0) ^ swA)]);
#pragma unroll
      for (int j = 0; j < 2; ++j) {
        const int tka = 16 * (nk0 + j) + l15;
        const s16x8 bk = *(const s16x8*)(&sm[BKO + tka * 256 + ((2 * c0) ^ swA)]);
        s[j] = __builtin_amdgcn_mfma_f32_16x16x32_bf16(aq, bk, s[j], 0, 0, 0);
      }
    }
#pragma unroll
    for (int j = 0; j < 2; ++j)
#pragma unroll
      for (int i = 0; i < 4; ++i) {
        const int tq = 16 * mq + 4 * qd + i;
        const int tk = 16 * (nk0 + j) + l15;
        *(float*)(&sm[BSO + tq * 256 + ((4 * tk) ^ ((tq & 7) << 4))]) = s[j][i] * SCALE;
      }
  }
  __syncthreads();

  // ====== Phase B: row softmax; ALL 8 waves, 8 rows each (2 per quad) =====
#pragma unroll
  for (int half = 0; half < 2; ++half) {
    const int r = 8 * wv + 2 * qd + half;
    float v[4];
#pragma unroll
    for (int j = 0; j < 4; ++j)
      v[j] = *(const float*)(&sm[BSO + r * 256 + ((4 * (16 * j + l15)) ^ ((r & 7) << 4))]);
    float m = fmaxf(fmaxf(v[0], v[1]), fmaxf(v[2], v[3]));
#pragma unroll
    for (int d = 1; d < 16; d <<= 1) m = fmaxf(m, __shfl_xor(m, d));
    float p[4], sum = 0.f;
#pragma unroll
    for (int j = 0; j < 4; ++j) {
      p[j] = exp2f((v[j] - m) * L2E);
      sum += p[j];
    }
#pragma unroll
    for (int d = 1; d < 16; d <<= 1) sum += __shfl_xor(sum, d);
    const float rinv = 1.0f / sum;
#pragma unroll
    for (int j = 0; j < 4; ++j)
      *(unsigned short*)(&sm[BPO + r * 128 + ((2 * (16 * j + l15)) ^ ((r & 7) << 4))]) =
          f2bf(p[j] * rinv);
  }
  __syncthreads();

  // ====== PV: ctx[tq][vd] = sum_tk P[tq][tk] V^T[vd][tk]; write global ======
  {
    const int mq = wv >> 1;              // tq tile
    const int nb = (wv & 1) * 4;         // vd tile base
    f32x4 cacc[4];
#pragma unroll
    for (int a = 0; a < 4; ++a) cacc[a] = (f32x4){0.f, 0.f, 0.f, 0.f};
    const int tqa = 16 * mq + l15;
#pragma unroll
    for (int ks = 0; ks < 2; ++ks) {
      const int c0 = 32 * ks + 8 * qd;
      const s16x8 ap = *(const s16x8*)(&sm[BPO + tqa * 128 + ((2 * c0) ^ swA)]);
#pragma unroll
      for (int j = 0; j < 4; ++j) {
        const int vda = 16 * (nb + j) + l15;
        const s16x8 bv = *(const s16x8*)(&sm[BVO + vda * 128 + ((2 * c0) ^ swA)]);
        cacc[j] = __builtin_amdgcn_mfma_f32_16x16x32_bf16(ap, bv, cacc[j], 0, 0, 0);
      }
    }
    unsigned short* ctxn = ctx + (size_t)nrel * 32768;
#pragma unroll
    for (int j = 0; j < 4; ++j) {
      const int vd = 16 * (nb + j) + l15;
      const int c  = h * 128 + vd;
      const int c8 = c >> 3, e = c & 7;
#pragma unroll
      for (int i = 0; i < 4; ++i) {
        const int tq = 16 * mq + 4 * qd + i;
        ctxn[((size_t)c8 * 64 + tq) * 8 + e] = f2bf(cacc[j][i]);
      }
    }
  }
}

// ====== out-proj: out[od][tok] = sum_c wo[od][c]*ctx[tok][c] + b, NCHW ======
#define OXS 0        // ctx slice dbuf: 2 x 16KB
#define OLDS 32768

__global__ void __launch_bounds__(512, 4)
outproj_kernel(const unsigned short* __restrict__ ctx,   // chunk base, tiled
               const unsigned short* __restrict__ wot,   // tiled w_out bf16
               const float* __restrict__ bout,
               float* __restrict__ out, int n0) {
  __shared__ __align__(16) unsigned char sm[OLDS];

  const int tid  = threadIdx.x;
  const int wv   = tid >> 6;
  const int lane = tid & 63;
  const int l15  = lane & 15;
  const int qd   = lane >> 4;

  const int nrel = blockIdx.x;
  const int n  = n0 + nrel;
  const int bb = n >> 8, hw = (n >> 4) & 15, ww = n & 15;
  const size_t wbase = (size_t)bb * C_TOT * CH_STRIDE
                     + (size_t)(hw * 8) * HWIMG + (size_t)(ww * 8);
  const unsigned short* ctxn = ctx + (size_t)nrel * 32768;

  f32x4 oacc[4][4];
#pragma unroll
  for (int a = 0; a < 4; ++a)
#pragma unroll
    for (int b2 = 0; b2 < 4; ++b2) oacc[a][b2] = (f32x4){0.f, 0.f, 0.f, 0.f};

  const unsigned short* orow[4];
#pragma unroll
  for (int mo = 0; mo < 4; ++mo)
    orow[mo] = wot + ((size_t)(4 * wv + mo) << 13) + l15 * 8;

  // prologue: DMA ctx slice 0
#pragma unroll
  for (int p = 0; p < 2; ++p)
    gload_lds16(ctxn + p * 4096 + tid * 8, &sm[OXS + p * 8192 + (wv << 10)]);
  __syncthreads();

  for (int s = 0; s < 4; ++s) {
    if (s < 3) {
#pragma unroll
      for (int p = 0; p < 2; ++p)
        gload_lds16(ctxn + (size_t)(s + 1) * 8192 + p * 4096 + tid * 8,
                    &sm[OXS + ((s + 1) & 1) * 16384 + p * 8192 + (wv << 10)]);
    }
    const int cur = OXS + (s & 1) * 16384;
#pragma unroll
    for (int j = 0; j < 4; ++j) {
      const int c8g = 16 * s + 4 * j + qd;
      const int lb = cur + ((4 * j + qd) << 10);
      s16x8 bc[4];
#pragma unroll
      for (int ni = 0; ni < 4; ++ni)
        bc[ni] = *(const s16x8*)(&sm[lb + (16 * ni + l15) * 16]);
#pragma unroll
      for (int mo = 0; mo < 4; ++mo) {
        const s16x8 af = *(const s16x8*)(orow[mo] + ((size_t)c8g << 7));
#pragma unroll
        for (int ni = 0; ni < 4; ++ni)
          oacc[mo][ni] = __builtin_amdgcn_mfma_f32_16x16x32_bf16(af, bc[ni], oacc[mo][ni], 0, 0, 0);
      }
    }
    __syncthreads();
  }

#pragma unroll
  for (int mo = 0; mo < 4; ++mo) {
    const int od0 = 64 * wv + 16 * mo + 4 * qd;
    float bo[4];
#pragma unroll
    for (int i = 0; i < 4; ++i) bo[i] = bout[od0 + i];
#pragma unroll
    for (int ni = 0; ni < 4; ++ni) {
      const int tok = 16 * ni + l15;
      const int r = tok >> 3, cc = tok & 7;
#pragma unroll
      for (int i = 0; i < 4; ++i) {
        out[wbase + (size_t)(od0 + i) * CH_STRIDE + (size_t)r * HWIMG + cc] =
            oacc[mo][ni][i] + bo[i];
      }
    }
  }
}

// ======================= R3 fused fallback =======================
#define QO    0
#define KO    16384
#define VO    32768
#define PO    49152
#define CTXO  57344
#define LDSB  73728

__global__ void __launch_bounds__(256)
pack_x_fb(const float* __restrict__ x, unsigned short* __restrict__ xw) {
  const int n  = blockIdx.x;
  const int bb = n >> 8, hw = (n >> 4) & 15, ww = n & 15;
  const size_t wbase = (size_t)bb * C_TOT * CH_STRIDE
                     + (size_t)(hw * 8) * HWIMG + (size_t)(ww * 8);
  const int tok = threadIdx.x & 63;
  const int q4  = threadIdx.x >> 6;
  const int r = tok >> 3, cc = tok & 7;
  const float* px = x + wbase + (size_t)r * HWIMG + cc;
  unsigned short* pw = xw + (size_t)n * 32768;
#pragma unroll 4
  for (int j = 0; j < 16; ++j) {
    const int o = q4 * 16 + j;
    float v[8];
#pragma unroll
    for (int k = 0; k < 8; ++k) v[k] = px[(size_t)(8 * o + k) * CH_STRIDE];
    s16x8 pk;
#pragma unroll
    for (int k = 0; k < 8; ++k) pk[k] = (short)f2bf(v[k]);
    *(s16x8*)(pw + ((size_t)o * 64 + tok) * 8) = pk;
  }
}

__global__ void __launch_bounds__(512, 2)
local_attn_kernel(const unsigned short* __restrict__ xw,
                  const float* __restrict__ bin,
                  const float* __restrict__ bout,
                  const unsigned short* __restrict__ wi,
                  const unsigned short* __restrict__ wo,
                  float* __restrict__ out) {
  __shared__ __align__(16) unsigned char sm[LDSB];
  const int tid  = threadIdx.x;
  const int wv   = tid >> 6;
  const int lane = tid & 63;
  const int l15  = lane & 15;
  const int qd   = lane >> 4;
  const int swA  = (l15 & 7) << 4;
  const int n  = blockIdx.x;
  const int bb = n >> 8;
  const int hw = (n >> 4) & 15;
  const int ww = n & 15;
  const size_t wbase = (size_t)bb * C_TOT * CH_STRIDE
                     + (size_t)(hw * 8) * HWIMG + (size_t)(ww * 8);
  const unsigned short* xww = xw + (size_t)n * 32768;
  f32x4 oacc[4][4];
#pragma unroll
  for (int a = 0; a < 4; ++a)
#pragma unroll
    for (int b2 = 0; b2 < 4; ++b2) oacc[a][b2] = (f32x4){0.f, 0.f, 0.f, 0.f};
  const float SCALE = 0.08838834764831845f;
  const float L2E   = 1.4426950408889634f;
  for (int h = 0; h < 4; ++h) {
    f32x4 acc[3][4];
#pragma unroll
    for (int a = 0; a < 3; ++a)
#pragma unroll
      for (int b2 = 0; b2 < 4; ++b2) acc[a][b2] = (f32x4){0.f, 0.f, 0.f, 0.f};
    const unsigned short* arow[3];
    int typ[3], d128s[3];
#pragma unroll
    for (int mi = 0; mi < 3; ++mi) {
      const int d0 = 48 * wv + 16 * mi;
      const int t = d0 >> 7;
      const int d128 = d0 & 127;
      typ[mi] = t; d128s[mi] = d128;
      arow[mi] = wi + (size_t)(t * 512 + h * 128 + d128 + l15) * 512;
    }
#pragma unroll 4
    for (int ks = 0; ks < 16; ++ks) {
      const int c0 = 32 * ks + 8 * qd;
      const int c8 = c0 >> 3;
      s16x8 bx[4];
#pragma unroll
      for (int ni = 0; ni < 4; ++ni)
        bx[ni] = *(const s16x8*)(xww + ((size_t)c8 * 64 + 16 * ni + l15) * 8);
#pragma unroll
      for (int mi = 0; mi < 3; ++mi) {
        const s16x8 af = *(const s16x8*)(arow[mi] + c0);
#pragma unroll
        for (int ni = 0; ni < 4; ++ni)
          acc[mi][ni] = __builtin_amdgcn_mfma_f32_16x16x32_bf16(af, bx[ni], acc[mi][ni], 0, 0, 0);
      }
    }
#pragma unroll
    for (int mi = 0; mi < 3; ++mi) {
      const int t = typ[mi], d128 = d128s[mi];
      const int e0 = t * 512 + h * 128 + d128 + 4 * qd;
      const float bi0 = bin[e0], bi1 = bin[e0 + 1], bi2 = bin[e0 + 2], bi3 = bin[e0 + 3];
#pragma unroll
      for (int ni = 0; ni < 4; ++ni) {
        const int tok = 16 * ni + l15;
        const unsigned short h0 = f2bf(acc[mi][ni][0] + bi0);
        const unsigned short h1 = f2bf(acc[mi][ni][1] + bi1);
        const unsigned short h2 = f2bf(acc[mi][ni][2] + bi2);
        const unsigned short h3 = f2bf(acc[mi][ni][3] + bi3);
        if (t < 2) {
          const unsigned lo = (unsigned)h0 | ((unsigned)h1 << 16);
          const unsigned hi = (unsigned)h2 | ((unsigned)h3 << 16);
          const unsigned long long pk = (unsigned long long)lo | ((unsigned long long)hi << 32);
          const int base = (t == 0) ? QO : KO;
          *(unsigned long long*)(&sm[base + tok * 256 + ((2 * (d128 + 4 * qd)) ^ swA)]) = pk;
        } else {
          const int vd = d128 + 4 * qd;
          *(unsigned short*)(&sm[VO + (vd    ) * 128 + ((2 * tok) ^ (((vd    ) & 7) << 4))]) = h0;
          *(unsigned short*)(&sm[VO + (vd + 1) * 128 + ((2 * tok) ^ (((vd + 1) & 7) << 4))]) = h1;
          *(unsigned short*)(&sm[VO + (vd + 2) * 128 + ((2 * tok) ^ (((vd + 2) & 7) << 4))]) = h2;
          *(unsigned short*)(&sm[VO + (vd + 3) * 128 + ((2 * tok) ^ (((vd + 3) & 7) << 4))]) = h3;
        }
      }
    }
    __syncthreads();
    if (wv < 4) {
      f32x4 s[4];
#pragma unroll
      for (int a = 0; a < 4; ++a) s[a] = (f32x4){0.f, 0.f, 0.f, 0.f};
      const int tqa = 16 * wv + l15;
#pragma unroll
      for (int ks = 0; ks < 4; ++ks) {
        const int c0 = 32 * ks + 8 * qd;
        const s16x8 aq = *(const s16x8*)(&sm[QO + tqa * 256 + ((2 * c0) ^ swA)]);
#pragma unroll
        for (int ni = 0; ni < 4; ++ni) {
          const int tk = 16 * ni + l15;
          const s16x8 bk = *(const s16x8*)(&sm[KO + tk * 256 + ((2 * c0) ^ swA)]);
          s[ni] = __builtin_amdgcn_mfma_f32_16x16x32_bf16(aq, bk, s[ni], 0, 0, 0);
        }
      }
      float sv[4][4];
#pragma unroll
      for (int ni = 0; ni < 4; ++ni)
#pragma unroll
        for (int i = 0; i < 4; ++i) sv[ni][i] = s[ni][i] * SCALE;
      float m[4];
#pragma unroll
      for (int i = 0; i < 4; ++i)
        m[i] = fmaxf(fmaxf(sv[0][i], sv[1][i]), fmaxf(sv[2][i], sv[3][i]));
#pragma unroll
      for (int d = 1; d < 16; d <<= 1)
#pragma unroll
        for (int i = 0; i < 4; ++i) m[i] = fmaxf(m[i], __shfl_xor(m[i], d));
      float p[4][4], sum[4] = {0.f, 0.f, 0.f, 0.f};
#pragma unroll
      for (int ni = 0; ni < 4; ++ni)
#pragma unroll
        for (int i = 0; i < 4; ++i) {
          p[ni][i] = exp2f((sv[ni][i] - m[i]) * L2E);
          sum[i] += p[ni][i];
        }
#pragma unroll
      for (int d = 1; d < 16; d <<= 1)
#pragma unroll
        for (int i = 0; i < 4; ++i) sum[i] += __shfl_xor(sum[i], d);
      float rinv[4];
#pragma unroll
      for (int i = 0; i < 4; ++i) rinv[i] = 1.0f / sum[i];
#pragma unroll
      for (int ni = 0; ni < 4; ++ni)
#pragma unroll
        for (int i = 0; i < 4; ++i) {
          const int tqr = 16 * wv + 4 * qd + i;
          const int tk = 16 * ni + l15;
          *(unsigned short*)(&sm[PO + tqr * 128 + ((2 * tk) ^ ((tqr & 7) << 4))]) =
              f2bf(p[ni][i] * rinv[i]);
        }
    }
    __syncthreads();
    {
      const int mq = wv >> 1;
      const int nb = (wv & 1) * 4;
      f32x4 cacc[4];
#pragma unroll
      for (int a = 0; a < 4; ++a) cacc[a] = (f32x4){0.f, 0.f, 0.f, 0.f};
      const int tqa = 16 * mq + l15;
#pragma unroll
      for (int ks = 0; ks < 2; ++ks) {
        const int c0 = 32 * ks + 8 * qd;
        const s16x8 ap = *(const s16x8*)(&sm[PO + tqa * 128 + ((2 * c0) ^ swA)]);
#pragma unroll
        for (int j = 0; j < 4; ++j) {
          const int vda = 16 * (nb + j) + l15;
          const s16x8 bv = *(const s16x8*)(&sm[VO + vda * 128 + ((2 * c0) ^ swA)]);
          cacc[j] = __builtin_amdgcn_mfma_f32_16x16x32_bf16(ap, bv, cacc[j], 0, 0, 0);
        }
      }
#pragma unroll
      for (int j = 0; j < 4; ++j)
#pragma unroll
        for (int i = 0; i < 4; ++i) {
          const int tq = 16 * mq + 4 * qd + i;
          const int vd = 16 * (nb + j) + l15;
          *(unsigned short*)(&sm[CTXO + tq * 256 + ((2 * vd) ^ ((tq & 7) << 4))]) =
              f2bf(cacc[j][i]);
        }
    }
    __syncthreads();
    {
#pragma unroll
      for (int ks = 0; ks < 4; ++ks) {
        const int c0 = 32 * ks + 8 * qd;
        s16x8 a2[4];
#pragma unroll
        for (int mo = 0; mo < 4; ++mo) {
          const int od = 64 * wv + 16 * mo + l15;
          a2[mo] = *(const s16x8*)(&wo[(size_t)od * 512 + 128 * h + c0]);
        }
        s16x8 bc[4];
#pragma unroll
        for (int ni = 0; ni < 4; ++ni) {
          const int tok = 16 * ni + l15;
          bc[ni] = *(const s16x8*)(&sm[CTXO + tok * 256 + ((2 * c0) ^ swA)]);
        }
#pragma unroll
        for (int mo = 0; mo < 4; ++mo)
#pragma unroll
          for (int ni = 0; ni < 4; ++ni)
            oacc[mo][ni] = __builtin_amdgcn_mfma_f32_16x16x32_bf16(a2[mo], bc[ni], oacc[mo][ni], 0, 0, 0);
      }
    }
  }
#pragma unroll
  for (int mo = 0; mo < 4; ++mo) {
    const int od0 = 64 * wv + 16 * mo + 4 * qd;
    float bo[4];
#pragma unroll
    for (int i = 0; i < 4; ++i) bo[i] = bout[od0 + i];
#pragma unroll
    for (int ni = 0; ni < 4; ++ni) {
      const int tok = 16 * ni + l15;
      const int r = tok >> 3, cc = tok & 7;
#pragma unroll
      for (int i = 0; i < 4; ++i) {
        out[wbase + (size_t)(od0 + i) * CH_STRIDE + (size_t)r * HWIMG + cc] =
            oacc[mo][ni][i] + bo[i];
      }
    }
  }
}

extern "C" void kernel_launch(void* const* d_in, const int* in_sizes, int n_in,
                              void* d_out, int out_size, void* d_ws, size_t ws_size,
                              hipStream_t stream) {
  const float* x     = (const float*)d_in[0];
  const float* w_in  = (const float*)d_in[1];
  const float* b_in  = (const float*)d_in[2];
  const float* w_out = (const float*)d_in[3];
  const float* b_out = (const float*)d_in[4];
  float* out = (float*)d_out;

  const size_t TIL_BYTES = (WIT_ELEMS + WOT_ELEMS) * 2ull;   // 2MB
  // prefer nc=1 (single launch pair, no serialization boundaries)
  int nc = 0;
  for (int c = 1; c <= 8; c <<= 1) {
    if (ws_size >= XW_BYTES + TIL_BYTES + CTX_BYTES_FULL / (size_t)c) { nc = c; break; }
  }

  if (nc) {
    unsigned short* xwp = (unsigned short*)d_ws;
    unsigned short* wit = xwp + XW_ELEMS;
    unsigned short* wot = wit + WIT_ELEMS;
    unsigned short* ctx = wot + WOT_ELEMS;
    conv_wt_kernel<<<4096, 256, 0, stream>>>(w_in, w_out, wit, wot);
    pack_x_kernel<<<2048, 256, 0, stream>>>(x, xwp);
    const int nwc = NWIN / nc;
    for (int k = 0; k < nc; ++k) {
      qkv_attn_kernel<<<nwc * 4, 512, 0, stream>>>(xwp, b_in, wit, ctx, k * nwc);
      outproj_kernel<<<nwc, 512, 0, stream>>>(ctx, wot, b_out, out, k * nwc);
    }
  } else {
    // R3 fused fallback (requires ws >= 137MB, proven available)
    unsigned short* xwp = (unsigned short*)d_ws;
    unsigned short* wbf = xwp + XW_ELEMS;
    conv_w_kernel<<<4096, 256, 0, stream>>>(w_in, w_out, wbf);
    pack_x_fb<<<NWIN, 256, 0, stream>>>(x, xwp);
    local_attn_kernel<<<NWIN, 512, 0, stream>>>(xwp, b_in, b_out,
                                                wbf, wbf + 786432, out);
  }
}

// Round 12
// 540.038 us; speedup vs baseline: 1.2620x; 1.0841x over previous
//
#include <hip/hip_runtime.h>

// LocalAttention: windowed MHA. B=8, C=512, H=W=128, WS=8
// -> N=2048 windows x L=64 tokens, NH=4, hd=128.
//
// Main path:
//   conv_pack: fused (w_in/w_out -> bf16 fragment-tiled) + (x -> bf16 tiled)
//   qkv_attn:  one block per (window, head), XCD-swizzled; QKV GEMM
//              (xw DMA-staged, tiled weights), 8-wave S+softmax, PV -> ctx.
//              s_setprio(1) around MFMA clusters (T5, phase-diverse blocks).
//   outproj:   GEMM out = w_out * ctx^T + b_out -> NCHW f32 (+setprio).
// Fallback: R3 fused kernel (plain weights).

typedef __attribute__((ext_vector_type(8))) short s16x8;   // 8 bf16
typedef __attribute__((ext_vector_type(4))) float f32x4;   // MFMA C/D

#define C_TOT 512
#define HWIMG 128
#define CH_STRIDE (HWIMG * HWIMG) /* 16384 */
#define NWIN 2048
#define XW_ELEMS ((size_t)NWIN * 64 * 512)     /* 67,108,864 bf16 */
#define XW_BYTES (XW_ELEMS * 2ull)             /* 134,217,728 B  */
#define WIT_ELEMS 786432ull                    /* tiled w_in  */
#define WOT_ELEMS 262144ull                    /* tiled w_out */
#define WBF_ELEMS 1048576ull
#define CTX_BYTES_FULL (XW_ELEMS * 2ull)       /* 134MB */

__device__ __forceinline__ unsigned short f2bf(float f) {
  unsigned u = __float_as_uint(f);
  u += 0x7FFFu + ((u >> 16) & 1u);       // RNE
  return (unsigned short)(u >> 16);
}

// async global->LDS DMA, 16B per lane; LDS dest = wave-uniform base + lane*16
__device__ __forceinline__ void gload_lds16(const void* g, void* l) {
  __builtin_amdgcn_global_load_lds(
      (const __attribute__((address_space(1))) unsigned int*)g,
      (__attribute__((address_space(3))) unsigned int*)l, 16, 0, 0);
}

// plain bf16 conversion (fallback path only)
__global__ void conv_w_kernel(const float* __restrict__ w_in,
                              const float* __restrict__ w_out,
                              unsigned short* __restrict__ wbf) {
  int i = blockIdx.x * blockDim.x + threadIdx.x;   // grid covers 1048576
  const int NIN = 3 * C_TOT * C_TOT;               // 786432
  float v = (i < NIN) ? w_in[i] : w_out[i - NIN];
  wbf[i] = f2bf(v);
}

// fused: blocks [0,4096) convert weights (fragment-tiled); [4096,6144) pack x.
//  wit[h4][m24][c8 64][l15 16][e8]; wot[m32][c8 64][l15 16][e8]
//  xw[n][c8 64][tok 64][8c]
__global__ void __launch_bounds__(256)
conv_pack_kernel(const float* __restrict__ w_in,
                 const float* __restrict__ w_out,
                 const float* __restrict__ x,
                 unsigned short* __restrict__ wit,
                 unsigned short* __restrict__ wot,
                 unsigned short* __restrict__ xw) {
  if (blockIdx.x < 4096) {
    int i = blockIdx.x * blockDim.x + threadIdx.x;   // 0..1048575
    const int NIN = 3 * C_TOT * C_TOT;               // 786432
    if (i < NIN) {
      const int e = i >> 9, c = i & 511;
      const int t = e >> 9, rem = e & 511;
      const int h = rem >> 7, d = rem & 127;
      const int m = t * 8 + (d >> 4), l = d & 15;
      const int c8 = c >> 3, ec = c & 7;
      wit[(((size_t)(h * 24 + m) * 64 + c8) << 7) + l * 8 + ec] = f2bf(w_in[i]);
    } else {
      const int j = i - NIN;                         // 0..262143
      const int od = j >> 9, c = j & 511;
      const int m = od >> 4, l = od & 15;
      const int c8 = c >> 3, ec = c & 7;
      wot[(((size_t)m * 64 + c8) << 7) + l * 8 + ec] = f2bf(w_out[j]);
    }
    return;
  }
  // ---- pack_x: fully-coalesced float4 reads + in-register transpose ----
  const int blk = blockIdx.x - 4096;
  const int bb  = blk >> 8;
  const int hw  = (blk >> 4) & 15;
  const int og4 = blk & 15;
  const int t   = threadIdx.x;
  const int p0  = 4 * t;                 // pixel in strip [0,1024)
  const int r   = p0 >> 7;               // row in window  [0,8)
  const int col0 = p0 & 127;             // col in strip   [0,128)
  const int n   = bb * 256 + hw * 16 + (col0 >> 3);
  const int tok0 = r * 8 + (col0 & 7);
  const float* xs = x + (size_t)bb * C_TOT * CH_STRIDE
                  + (size_t)hw * 1024 + p0;
  unsigned short* pw = xw + (size_t)n * 32768;
#pragma unroll
  for (int jo = 0; jo < 4; ++jo) {
    const int o = og4 * 4 + jo;          // channel octet 0..63
    float4 f[8];
#pragma unroll
    for (int k = 0; k < 8; ++k)
      f[k] = *(const float4*)(xs + (size_t)(8 * o + k) * CH_STRIDE);
#pragma unroll
    for (int i = 0; i < 4; ++i) {
      s16x8 pk;
      if (i == 0) {
        pk[0]=(short)f2bf(f[0].x); pk[1]=(short)f2bf(f[1].x); pk[2]=(short)f2bf(f[2].x); pk[3]=(short)f2bf(f[3].x);
        pk[4]=(short)f2bf(f[4].x); pk[5]=(short)f2bf(f[5].x); pk[6]=(short)f2bf(f[6].x); pk[7]=(short)f2bf(f[7].x);
      } else if (i == 1) {
        pk[0]=(short)f2bf(f[0].y); pk[1]=(short)f2bf(f[1].y); pk[2]=(short)f2bf(f[2].y); pk[3]=(short)f2bf(f[3].y);
        pk[4]=(short)f2bf(f[4].y); pk[5]=(short)f2bf(f[5].y); pk[6]=(short)f2bf(f[6].y); pk[7]=(short)f2bf(f[7].y);
      } else if (i == 2) {
        pk[0]=(short)f2bf(f[0].z); pk[1]=(short)f2bf(f[1].z); pk[2]=(short)f2bf(f[2].z); pk[3]=(short)f2bf(f[3].z);
        pk[4]=(short)f2bf(f[4].z); pk[5]=(short)f2bf(f[5].z); pk[6]=(short)f2bf(f[6].z); pk[7]=(short)f2bf(f[7].z);
      } else {
        pk[0]=(short)f2bf(f[0].w); pk[1]=(short)f2bf(f[1].w); pk[2]=(short)f2bf(f[2].w); pk[3]=(short)f2bf(f[3].w);
        pk[4]=(short)f2bf(f[4].w); pk[5]=(short)f2bf(f[5].w); pk[6]=(short)f2bf(f[6].w); pk[7]=(short)f2bf(f[7].w);
      }
      *(s16x8*)(pw + ((size_t)o * 64 + tok0 + i) * 8) = pk;
    }
  }
}

// ---- kernel B LDS layout (80KB) ----
#define BQO 0        // Q [tok 64][d 128] bf16, row 256B, swz ((tok&7)<<4)
#define BKO 16384
#define BVO 32768    // V^T [d 128][tok 64] bf16, row 128B, swz ((d&7)<<4)
#define BXS 49152    // xw slice dbuf: 2 x 16KB (dead after GEMM)
#define BPO 49152    // P [tq 64][tk 64] bf16 - OVERLAYS stage (dead)
#define BSO 57344    // S [tq 64][tk 64] f32, row 256B - OVERLAYS stage (dead)
#define BLDS 81920

__global__ void __launch_bounds__(512, 4)
qkv_attn_kernel(const unsigned short* __restrict__ xw,   // tiled bf16 x
                const float* __restrict__ bin,
                const unsigned short* __restrict__ wit,  // tiled w_in bf16
                unsigned short* __restrict__ ctx,        // chunk base, tiled
                int n0) {
  __shared__ __align__(16) unsigned char sm[BLDS];

  const int tid  = threadIdx.x;
  const int wv   = tid >> 6;      // wave 0..7
  const int lane = tid & 63;
  const int l15  = lane & 15;
  const int qd   = lane >> 4;
  const int swA  = (l15 & 7) << 4;

  // XCD swizzle: blk = 32k + 8h + g -> window wrel = 8k + g, head h.
  const int blk = blockIdx.x;
  const int g   = blk & 7;
  const int q   = blk >> 3;
  const int h   = q & 3;
  const int nrel = (q >> 2) * 8 + g;
  const unsigned short* xww = xw + (size_t)(n0 + nrel) * 32768;

  const float SCALE = 0.08838834764831845f;  // 1/sqrt(128)
  const float L2E   = 1.4426950408889634f;

  // ====== QKV GEMM: R8-proven map — wave wv owns dims [48wv, 48wv+48) ======
  f32x4 acc[3][4];
#pragma unroll
  for (int a = 0; a < 3; ++a)
#pragma unroll
    for (int b2 = 0; b2 < 4; ++b2) acc[a][b2] = (f32x4){0.f, 0.f, 0.f, 0.f};

  const unsigned short* arow[3];
  int typ[3], d128s[3];
#pragma unroll
  for (int mi = 0; mi < 3; ++mi) {
    const int d0 = 48 * wv + 16 * mi;     // dim base within QKV-384
    const int t = d0 >> 7;                // 0=Q 1=K 2=V
    const int d128 = d0 & 127;
    typ[mi] = t; d128s[mi] = d128;
    const int m = t * 8 + (d128 >> 4);    // tile index within head
    arow[mi] = wit + ((size_t)(h * 24 + m) << 13) + l15 * 8;
  }

  // prologue: DMA slice 0 (2 passes x 8KB)
#pragma unroll
  for (int p = 0; p < 2; ++p)
    gload_lds16(xww + p * 4096 + tid * 8, &sm[BXS + p * 8192 + (wv << 10)]);
  __syncthreads();

  for (int s = 0; s < 4; ++s) {
    if (s < 3) {
#pragma unroll
      for (int p = 0; p < 2; ++p)
        gload_lds16(xww + (size_t)(s + 1) * 8192 + p * 4096 + tid * 8,
                    &sm[BXS + ((s + 1) & 1) * 16384 + p * 8192 + (wv << 10)]);
    }
    const int cur = BXS + (s & 1) * 16384;
#pragma unroll
    for (int j = 0; j < 4; ++j) {
      const int c8g = 16 * s + 4 * j + qd;         // global channel octet
      const int lb = cur + ((4 * j + qd) << 10);   // local c8 block
      s16x8 bx[4];
#pragma unroll
      for (int ni = 0; ni < 4; ++ni)
        bx[ni] = *(const s16x8*)(&sm[lb + (16 * ni + l15) * 16]);
      s16x8 af[3];
#pragma unroll
      for (int mi = 0; mi < 3; ++mi)
        af[mi] = *(const s16x8*)(arow[mi] + ((size_t)c8g << 7));
      __builtin_amdgcn_s_setprio(1);
#pragma unroll
      for (int mi = 0; mi < 3; ++mi)
#pragma unroll
        for (int ni = 0; ni < 4; ++ni)
          acc[mi][ni] = __builtin_amdgcn_mfma_f32_16x16x32_bf16(af[mi], bx[ni], acc[mi][ni], 0, 0, 0);
      __builtin_amdgcn_s_setprio(0);
    }
    __syncthreads();   // drains vmcnt (DMA done) + all reads of cur complete
  }

  // epilogue (R8-proven): Q/K -> [tok][d] packed b64; V -> [d][tok] scatter
#pragma unroll
  for (int mi = 0; mi < 3; ++mi) {
    const int t = typ[mi], d128 = d128s[mi];
    const int e0 = t * 512 + h * 128 + d128 + 4 * qd;
    const float bi0 = bin[e0], bi1 = bin[e0 + 1], bi2 = bin[e0 + 2], bi3 = bin[e0 + 3];
#pragma unroll
    for (int ni = 0; ni < 4; ++ni) {
      const int tok = 16 * ni + l15;
      const unsigned short h0 = f2bf(acc[mi][ni][0] + bi0);
      const unsigned short h1 = f2bf(acc[mi][ni][1] + bi1);
      const unsigned short h2 = f2bf(acc[mi][ni][2] + bi2);
      const unsigned short h3 = f2bf(acc[mi][ni][3] + bi3);
      if (t < 2) {
        const unsigned lo = (unsigned)h0 | ((unsigned)h1 << 16);
        const unsigned hi = (unsigned)h2 | ((unsigned)h3 << 16);
        const unsigned long long pk = (unsigned long long)lo | ((unsigned long long)hi << 32);
        const int base = (t == 0) ? BQO : BKO;
        *(unsigned long long*)(&sm[base + tok * 256 + ((2 * (d128 + 4 * qd)) ^ swA)]) = pk;
      } else {
        const int vd = d128 + 4 * qd;
        *(unsigned short*)(&sm[BVO + (vd    ) * 128 + ((2 * tok) ^ (((vd    ) & 7) << 4))]) = h0;
        *(unsigned short*)(&sm[BVO + (vd + 1) * 128 + ((2 * tok) ^ (((vd + 1) & 7) << 4))]) = h1;
        *(unsigned short*)(&sm[BVO + (vd + 2) * 128 + ((2 * tok) ^ (((vd + 2) & 7) << 4))]) = h2;
        *(unsigned short*)(&sm[BVO + (vd + 3) * 128 + ((2 * tok) ^ (((vd + 3) & 7) << 4))]) = h3;
      }
    }
  }
  __syncthreads();

  // ====== Phase A: S = QK^T * scale -> f32 LDS; ALL 8 waves, 2 tiles each ==
  {
    const int mq  = wv >> 1;             // q-tile 0..3
    const int nk0 = (wv & 1) * 2;        // k-tile pair base
    f32x4 s[2];
#pragma unroll
    for (int a = 0; a < 2; ++a) s[a] = (f32x4){0.f, 0.f, 0.f, 0.f};
    const int tqa = 16 * mq + l15;
#pragma unroll
    for (int ks = 0; ks < 4; ++ks) {
      const int c0 = 32 * ks + 8 * qd;
      const s16x8 aq = *(const s16x8*)(&sm[BQO + tqa * 256 + ((2 * c0) ^ swA)]);
      s16x8 bk[2];
#pragma unroll
      for (int j = 0; j < 2; ++j) {
        const int tka = 16 * (nk0 + j) + l15;
        bk[j] = *(const s16x8*)(&sm[BKO + tka * 256 + ((2 * c0) ^ swA)]);
      }
      __builtin_amdgcn_s_setprio(1);
#pragma unroll
      for (int j = 0; j < 2; ++j)
        s[j] = __builtin_amdgcn_mfma_f32_16x16x32_bf16(aq, bk[j], s[j], 0, 0, 0);
      __builtin_amdgcn_s_setprio(0);
    }
#pragma unroll
    for (int j = 0; j < 2; ++j)
#pragma unroll
      for (int i = 0; i < 4; ++i) {
        const int tq = 16 * mq + 4 * qd + i;
        const int tk = 16 * (nk0 + j) + l15;
        *(float*)(&sm[BSO + tq * 256 + ((4 * tk) ^ ((tq & 7) << 4))]) = s[j][i] * SCALE;
      }
  }
  __syncthreads();

  // ====== Phase B: row softmax; ALL 8 waves, 8 rows each (2 per quad) =====
#pragma unroll
  for (int half = 0; half < 2; ++half) {
    const int r = 8 * wv + 2 * qd + half;
    float v[4];
#pragma unroll
    for (int j = 0; j < 4; ++j)
      v[j] = *(const float*)(&sm[BSO + r * 256 + ((4 * (16 * j + l15)) ^ ((r & 7) << 4))]);
    float m = fmaxf(fmaxf(v[0], v[1]), fmaxf(v[2], v[3]));
#pragma unroll
    for (int d = 1; d < 16; d <<= 1) m = fmaxf(m, __shfl_xor(m, d));
    float p[4], sum = 0.f;
#pragma unroll
    for (int j = 0; j < 4; ++j) {
      p[j] = exp2f((v[j] - m) * L2E);
      sum += p[j];
    }
#pragma unroll
    for (int d = 1; d < 16; d <<= 1) sum += __shfl_xor(sum, d);
    const float rinv = 1.0f / sum;
#pragma unroll
    for (int j = 0; j < 4; ++j)
      *(unsigned short*)(&sm[BPO + r * 128 + ((2 * (16 * j + l15)) ^ ((r & 7) << 4))]) =
          f2bf(p[j] * rinv);
  }
  __syncthreads();

  // ====== PV: ctx[tq][vd] = sum_tk P[tq][tk] V^T[vd][tk]; write global ======
  {
    const int mq = wv >> 1;              // tq tile
    const int nb = (wv & 1) * 4;         // vd tile base
    f32x4 cacc[4];
#pragma unroll
    for (int a = 0; a < 4; ++a) cacc[a] = (f32x4){0.f, 0.f, 0.f, 0.f};
    const int tqa = 16 * mq + l15;
#pragma unroll
    for (int ks = 0; ks < 2; ++ks) {
      const int c0 = 32 * ks + 8 * qd;
      const s16x8 ap = *(const s16x8*)(&sm[BPO + tqa * 128 + ((2 * c0) ^ swA)]);
      s16x8 bv[4];
#pragma unroll
      for (int j = 0; j < 4; ++j) {
        const int vda = 16 * (nb + j) + l15;
        bv[j] = *(const s16x8*)(&sm[BVO + vda * 128 + ((2 * c0) ^ swA)]);
      }
      __builtin_amdgcn_s_setprio(1);
#pragma unroll
      for (int j = 0; j < 4; ++j)
        cacc[j] = __builtin_amdgcn_mfma_f32_16x16x32_bf16(ap, bv[j], cacc[j], 0, 0, 0);
      __builtin_amdgcn_s_setprio(0);
    }
    unsigned short* ctxn = ctx + (size_t)nrel * 32768;
#pragma unroll
    for (int j = 0; j < 4; ++j) {
      const int vd = 16 * (nb + j) + l15;
      const int c  = h * 128 + vd;
      const int c8 = c >> 3, e = c & 7;
#pragma unroll
      for (int i = 0; i < 4; ++i) {
        const int tq = 16 * mq + 4 * qd + i;
        ctxn[((size_t)c8 * 64 + tq) * 8 + e] = f2bf(cacc[j][i]);
      }
    }
  }
}

// ====== out-proj: out[od][tok] = sum_c wo[od][c]*ctx[tok][c] + b, NCHW ======
#define OXS 0        // ctx slice dbuf: 2 x 16KB
#define OLDS 32768

__global__ void __launch_bounds__(512, 4)
outproj_kernel(const unsigned short* __restrict__ ctx,   // chunk base, tiled
               const unsigned short* __restrict__ wot,   // tiled w_out bf16
               const float* __restrict__ bout,
               float* __restrict__ out, int n0) {
  __shared__ __align__(16) unsigned char sm[OLDS];

  const int tid  = threadIdx.x;
  const int wv   = tid >> 6;
  const int lane = tid & 63;
  const int l15  = lane & 15;
  const int qd   = lane >> 4;

  const int nrel = blockIdx.x;
  const int n  = n0 + nrel;
  const int bb = n >> 8, hw = (n >> 4) & 15, ww = n & 15;
  const size_t wbase = (size_t)bb * C_TOT * CH_STRIDE
                     + (size_t)(hw * 8) * HWIMG + (size_t)(ww * 8);
  const unsigned short* ctxn = ctx + (size_t)nrel * 32768;

  f32x4 oacc[4][4];
#pragma unroll
  for (int a = 0; a < 4; ++a)
#pragma unroll
    for (int b2 = 0; b2 < 4; ++b2) oacc[a][b2] = (f32x4){0.f, 0.f, 0.f, 0.f};

  const unsigned short* orow[4];
#pragma unroll
  for (int mo = 0; mo < 4; ++mo)
    orow[mo] = wot + ((size_t)(4 * wv + mo) << 13) + l15 * 8;

  // prologue: DMA ctx slice 0
#pragma unroll
  for (int p = 0; p < 2; ++p)
    gload_lds16(ctxn + p * 4096 + tid * 8, &sm[OXS + p * 8192 + (wv << 10)]);
  __syncthreads();

  for (int s = 0; s < 4; ++s) {
    if (s < 3) {
#pragma unroll
      for (int p = 0; p < 2; ++p)
        gload_lds16(ctxn + (size_t)(s + 1) * 8192 + p * 4096 + tid * 8,
                    &sm[OXS + ((s + 1) & 1) * 16384 + p * 8192 + (wv << 10)]);
    }
    const int cur = OXS + (s & 1) * 16384;
#pragma unroll
    for (int j = 0; j < 4; ++j) {
      const int c8g = 16 * s + 4 * j + qd;
      const int lb = cur + ((4 * j + qd) << 10);
      s16x8 bc[4];
#pragma unroll
      for (int ni = 0; ni < 4; ++ni)
        bc[ni] = *(const s16x8*)(&sm[lb + (16 * ni + l15) * 16]);
      s16x8 af[4];
#pragma unroll
      for (int mo = 0; mo < 4; ++mo)
        af[mo] = *(const s16x8*)(orow[mo] + ((size_t)c8g << 7));
      __builtin_amdgcn_s_setprio(1);
#pragma unroll
      for (int mo = 0; mo < 4; ++mo)
#pragma unroll
        for (int ni = 0; ni < 4; ++ni)
          oacc[mo][ni] = __builtin_amdgcn_mfma_f32_16x16x32_bf16(af[mo], bc[ni], oacc[mo][ni], 0, 0, 0);
      __builtin_amdgcn_s_setprio(0);
    }
    __syncthreads();
  }

#pragma unroll
  for (int mo = 0; mo < 4; ++mo) {
    const int od0 = 64 * wv + 16 * mo + 4 * qd;
    float bo[4];
#pragma unroll
    for (int i = 0; i < 4; ++i) bo[i] = bout[od0 + i];
#pragma unroll
    for (int ni = 0; ni < 4; ++ni) {
      const int tok = 16 * ni + l15;
      const int r = tok >> 3, cc = tok & 7;
#pragma unroll
      for (int i = 0; i < 4; ++i) {
        out[wbase + (size_t)(od0 + i) * CH_STRIDE + (size_t)r * HWIMG + cc] =
            oacc[mo][ni][i] + bo[i];
      }
    }
  }
}

// ======================= R3 fused fallback =======================
#define QO    0
#define KO    16384
#define VO    32768
#define PO    49152
#define CTXO  57344
#define LDSB  73728

__global__ void __launch_bounds__(256)
pack_x_fb(const float* __restrict__ x, unsigned short* __restrict__ xw) {
  const int n  = blockIdx.x;
  const int bb = n >> 8, hw = (n >> 4) & 15, ww = n & 15;
  const size_t wbase = (size_t)bb * C_TOT * CH_STRIDE
                     + (size_t)(hw * 8) * HWIMG + (size_t)(ww * 8);
  const int tok = threadIdx.x & 63;
  const int q4  = threadIdx.x >> 6;
  const int r = tok >> 3, cc = tok & 7;
  const float* px = x + wbase + (size_t)r * HWIMG + cc;
  unsigned short* pw = xw + (size_t)n * 32768;
#pragma unroll 4
  for (int j = 0; j < 16; ++j) {
    const int o = q4 * 16 + j;
    float v[8];
#pragma unroll
    for (int k = 0; k < 8; ++k) v[k] = px[(size_t)(8 * o + k) * CH_STRIDE];
    s16x8 pk;
#pragma unroll
    for (int k = 0; k < 8; ++k) pk[k] = (short)f2bf(v[k]);
    *(s16x8*)(pw + ((size_t)o * 64 + tok) * 8) = pk;
  }
}

__global__ void __launch_bounds__(512, 2)
local_attn_kernel(const unsigned short* __restrict__ xw,
                  const float* __restrict__ bin,
                  const float* __restrict__ bout,
                  const unsigned short* __restrict__ wi,
                  const unsigned short* __restrict__ wo,
                  float* __restrict__ out) {
  __shared__ __align__(16) unsigned char sm[LDSB];
  const int tid  = threadIdx.x;
  const int wv   = tid >> 6;
  const int lane = tid & 63;
  const int l15  = lane & 15;
  const int qd   = lane >> 4;
  const int swA  = (l15 & 7) << 4;
  const int n  = blockIdx.x;
  const int bb = n >> 8;
  const int hw = (n >> 4) & 15;
  const int ww = n & 15;
  const size_t wbase = (size_t)bb * C_TOT * CH_STRIDE
                     + (size_t)(hw * 8) * HWIMG + (size_t)(ww * 8);
  const unsigned short* xww = xw + (size_t)n * 32768;
  f32x4 oacc[4][4];
#pragma unroll
  for (int a = 0; a < 4; ++a)
#pragma unroll
    for (int b2 = 0; b2 < 4; ++b2) oacc[a][b2] = (f32x4){0.f, 0.f, 0.f, 0.f};
  const float SCALE = 0.08838834764831845f;
  const float L2E   = 1.4426950408889634f;
  for (int h = 0; h < 4; ++h) {
    f32x4 acc[3][4];
#pragma unroll
    for (int a = 0; a < 3; ++a)
#pragma unroll
      for (int b2 = 0; b2 < 4; ++b2) acc[a][b2] = (f32x4){0.f, 0.f, 0.f, 0.f};
    const unsigned short* arow[3];
    int typ[3], d128s[3];
#pragma unroll
    for (int mi = 0; mi < 3; ++mi) {
      const int d0 = 48 * wv + 16 * mi;
      const int t = d0 >> 7;
      const int d128 = d0 & 127;
      typ[mi] = t; d128s[mi] = d128;
      arow[mi] = wi + (size_t)(t * 512 + h * 128 + d128 + l15) * 512;
    }
#pragma unroll 4
    for (int ks = 0; ks < 16; ++ks) {
      const int c0 = 32 * ks + 8 * qd;
      const int c8 = c0 >> 3;
      s16x8 bx[4];
#pragma unroll
      for (int ni = 0; ni < 4; ++ni)
        bx[ni] = *(const s16x8*)(xww + ((size_t)c8 * 64 + 16 * ni + l15) * 8);
#pragma unroll
      for (int mi = 0; mi < 3; ++mi) {
        const s16x8 af = *(const s16x8*)(arow[mi] + c0);
#pragma unroll
        for (int ni = 0; ni < 4; ++ni)
          acc[mi][ni] = __builtin_amdgcn_mfma_f32_16x16x32_bf16(af, bx[ni], acc[mi][ni], 0, 0, 0);
      }
    }
#pragma unroll
    for (int mi = 0; mi < 3; ++mi) {
      const int t = typ[mi], d128 = d128s[mi];
      const int e0 = t * 512 + h * 128 + d128 + 4 * qd;
      const float bi0 = bin[e0], bi1 = bin[e0 + 1], bi2 = bin[e0 + 2], bi3 = bin[e0 + 3];
#pragma unroll
      for (int ni = 0; ni < 4; ++ni) {
        const int tok = 16 * ni + l15;
        const unsigned short h0 = f2bf(acc[mi][ni][0] + bi0);
        const unsigned short h1 = f2bf(acc[mi][ni][1] + bi1);
        const unsigned short h2 = f2bf(acc[mi][ni][2] + bi2);
        const unsigned short h3 = f2bf(acc[mi][ni][3] + bi3);
        if (t < 2) {
          const unsigned lo = (unsigned)h0 | ((unsigned)h1 << 16);
          const unsigned hi = (unsigned)h2 | ((unsigned)h3 << 16);
          const unsigned long long pk = (unsigned long long)lo | ((unsigned long long)hi << 32);
          const int base = (t == 0) ? QO : KO;
          *(unsigned long long*)(&sm[base + tok * 256 + ((2 * (d128 + 4 * qd)) ^ swA)]) = pk;
        } else {
          const int vd = d128 + 4 * qd;
          *(unsigned short*)(&sm[VO + (vd    ) * 128 + ((2 * tok) ^ (((vd    ) & 7) << 4))]) = h0;
          *(unsigned short*)(&sm[VO + (vd + 1) * 128 + ((2 * tok) ^ (((vd + 1) & 7) << 4))]) = h1;
          *(unsigned short*)(&sm[VO + (vd + 2) * 128 + ((2 * tok) ^ (((vd + 2) & 7) << 4))]) = h2;
          *(unsigned short*)(&sm[VO + (vd + 3) * 128 + ((2 * tok) ^ (((vd + 3) & 7) << 4))]) = h3;
        }
      }
    }
    __syncthreads();
    if (wv < 4) {
      f32x4 s[4];
#pragma unroll
      for (int a = 0; a < 4; ++a) s[a] = (f32x4){0.f, 0.f, 0.f, 0.f};
      const int tqa = 16 * wv + l15;
#pragma unroll
      for (int ks = 0; ks < 4; ++ks) {
        const int c0 = 32 * ks + 8 * qd;
        const s16x8 aq = *(const s16x8*)(&sm[QO + tqa * 256 + ((2 * c0) ^ swA)]);
#pragma unroll
        for (int ni = 0; ni < 4; ++ni) {
          const int tk = 16 * ni + l15;
          const s16x8 bk = *(const s16x8*)(&sm[KO + tk * 256 + ((2 * c0) ^ swA)]);
          s[ni] = __builtin_amdgcn_mfma_f32_16x16x32_bf16(aq, bk, s[ni], 0, 0, 0);
        }
      }
      float sv[4][4];
#pragma unroll
      for (int ni = 0; ni < 4; ++ni)
#pragma unroll
        for (int i = 0; i < 4; ++i) sv[ni][i] = s[ni][i] * SCALE;
      float m[4];
#pragma unroll
      for (int i = 0; i < 4; ++i)
        m[i] = fmaxf(fmaxf(sv[0][i], sv[1][i]), fmaxf(sv[2][i], sv[3][i]));
#pragma unroll
      for (int d = 1; d < 16; d <<= 1)
#pragma unroll
        for (int i = 0; i < 4; ++i) m[i] = fmaxf(m[i], __shfl_xor(m[i], d));
      float p[4][4], sum[4] = {0.f, 0.f, 0.f, 0.f};
#pragma unroll
      for (int ni = 0; ni < 4; ++ni)
#pragma unroll
        for (int i = 0; i < 4; ++i) {
          p[ni][i] = exp2f((sv[ni][i] - m[i]) * L2E);
          sum[i] += p[ni][i];
        }
#pragma unroll
      for (int d = 1; d < 16; d <<= 1)
#pragma unroll
        for (int i = 0; i < 4; ++i) sum[i] += __shfl_xor(sum[i], d);
      float rinv[4];
#pragma unroll
      for (int i = 0; i < 4; ++i) rinv[i] = 1.0f / sum[i];
#pragma unroll
      for (int ni = 0; ni < 4; ++ni)
#pragma unroll
        for (int i = 0; i < 4; ++i) {
          const int tqr = 16 * wv + 4 * qd + i;
          const int tk = 16 * ni + l15;
          *(unsigned short*)(&sm[PO + tqr * 128 + ((2 * tk) ^ ((tqr & 7) << 4))]) =
              f2bf(p[ni][i] * rinv[i]);
        }
    }
    __syncthreads();
    {
      const int mq = wv >> 1;
      const int nb = (wv & 1) * 4;
      f32x4 cacc[4];
#pragma unroll
      for (int a = 0; a < 4; ++a) cacc[a] = (f32x4){0.f, 0.f, 0.f, 0.f};
      const int tqa = 16 * mq + l15;
#pragma unroll
      for (int ks = 0; ks < 2; ++ks) {
        const int c0 = 32 * ks + 8 * qd;
        const s16x8 ap = *(const s16x8*)(&sm[PO + tqa * 128 + ((2 * c0) ^ swA)]);
#pragma unroll
        for (int j = 0; j < 4; ++j) {
          const int vda = 16 * (nb + j) + l15;
          const s16x8 bv = *(const s16x8*)(&sm[VO + vda * 128 + ((2 * c0) ^ swA)]);
          cacc[j] = __builtin_amdgcn_mfma_f32_16x16x32_bf16(ap, bv, cacc[j], 0, 0, 0);
        }
      }
#pragma unroll
      for (int j = 0; j < 4; ++j)
#pragma unroll
        for (int i = 0; i < 4; ++i) {
          const int tq = 16 * mq + 4 * qd + i;
          const int vd = 16 * (nb + j) + l15;
          *(unsigned short*)(&sm[CTXO + tq * 256 + ((2 * vd) ^ ((tq & 7) << 4))]) =
              f2bf(cacc[j][i]);
        }
    }
    __syncthreads();
    {
#pragma unroll
      for (int ks = 0; ks < 4; ++ks) {
        const int c0 = 32 * ks + 8 * qd;
        s16x8 a2[4];
#pragma unroll
        for (int mo = 0; mo < 4; ++mo) {
          const int od = 64 * wv + 16 * mo + l15;
          a2[mo] = *(const s16x8*)(&wo[(size_t)od * 512 + 128 * h + c0]);
        }
        s16x8 bc[4];
#pragma unroll
        for (int ni = 0; ni < 4; ++ni) {
          const int tok = 16 * ni + l15;
          bc[ni] = *(const s16x8*)(&sm[CTXO + tok * 256 + ((2 * c0) ^ swA)]);
        }
#pragma unroll
        for (int mo = 0; mo < 4; ++mo)
#pragma unroll
          for (int ni = 0; ni < 4; ++ni)
            oacc[mo][ni] = __builtin_amdgcn_mfma_f32_16x16x32_bf16(a2[mo], bc[ni], oacc[mo][ni], 0, 0, 0);
      }
    }
  }
#pragma unroll
  for (int mo = 0; mo < 4; ++mo) {
    const int od0 = 64 * wv + 16 * mo + 4 * qd;
    float bo[4];
#pragma unroll
    for (int i = 0; i < 4; ++i) bo[i] = bout[od0 + i];
#pragma unroll
    for (int ni = 0; ni < 4; ++ni) {
      const int tok = 16 * ni + l15;
      const int r = tok >> 3, cc = tok & 7;
#pragma unroll
      for (int i = 0; i < 4; ++i) {
        out[wbase + (size_t)(od0 + i) * CH_STRIDE + (size_t)r * HWIMG + cc] =
            oacc[mo][ni][i] + bo[i];
      }
    }
  }
}

extern "C" void kernel_launch(void* const* d_in, const int* in_sizes, int n_in,
                              void* d_out, int out_size, void* d_ws, size_t ws_size,
                              hipStream_t stream) {
  const float* x     = (const float*)d_in[0];
  const float* w_in  = (const float*)d_in[1];
  const float* b_in  = (const float*)d_in[2];
  const float* w_out = (const float*)d_in[3];
  const float* b_out = (const float*)d_in[4];
  float* out = (float*)d_out;

  const size_t TIL_BYTES = (WIT_ELEMS + WOT_ELEMS) * 2ull;   // 2MB
  // prefer nc=1 (single launch pair, no serialization boundaries)
  int nc = 0;
  for (int c = 1; c <= 8; c <<= 1) {
    if (ws_size >= XW_BYTES + TIL_BYTES + CTX_BYTES_FULL / (size_t)c) { nc = c; break; }
  }

  if (nc) {
    unsigned short* xwp = (unsigned short*)d_ws;
    unsigned short* wit = xwp + XW_ELEMS;
    unsigned short* wot = wit + WIT_ELEMS;
    unsigned short* ctx = wot + WOT_ELEMS;
    conv_pack_kernel<<<6144, 256, 0, stream>>>(w_in, w_out, x, wit, wot, xwp);
    const int nwc = NWIN / nc;
    for (int k = 0; k < nc; ++k) {
      qkv_attn_kernel<<<nwc * 4, 512, 0, stream>>>(xwp, b_in, wit, ctx, k * nwc);
      outproj_kernel<<<nwc, 512, 0, stream>>>(ctx, wot, b_out, out, k * nwc);
    }
  } else {
    // R3 fused fallback (requires ws >= 137MB, proven available)
    unsigned short* xwp = (unsigned short*)d_ws;
    unsigned short* wbf = xwp + XW_ELEMS;
    conv_w_kernel<<<4096, 256, 0, stream>>>(w_in, w_out, wbf);
    pack_x_fb<<<NWIN, 256, 0, stream>>>(x, xwp);
    local_attn_kernel<<<NWIN, 512, 0, stream>>>(xwp, b_in, b_out,
                                                wbf, wbf + 786432, out);
  }
}